// Round 1
// baseline (2464.690 us; speedup 1.0000x reference)
//
#include <hip/hip_runtime.h>
#include <math.h>

// Problem constants (match reference)
#define NN    4096
#define EE    131072
#define ENE   (EE + NN)      // edges + self loops = 135168
#define IND   128
#define HH    8
#define HIDC  64
#define DD    512
#define D3    1536
#define DFF2  256

__device__ __forceinline__ float lrelu02(float x) { return x >= 0.f ? x : 0.2f * x; }

// ---------------------------------------------------------------------------
// Generic C[M,Nc] = A[M,K] @ Bw[Nc,K]^T (+bias, optional relu). 64x64 tile,
// BK=16, 256 threads, 4x4 micro-tile. LDS padded +1 (conflict-free b32 reads).
// ---------------------------------------------------------------------------
__global__ __launch_bounds__(256) void gemm_bt(const float* __restrict__ A,
                                               const float* __restrict__ Bw,
                                               const float* __restrict__ bias,
                                               float* __restrict__ C,
                                               int M, int K, int Nc, int relu)
{
    __shared__ float As[16][65];
    __shared__ float Bs[16][65];
    const int t  = threadIdx.x;
    const int bm = blockIdx.y * 64, bn = blockIdx.x * 64;
    const int tr = t >> 4, tc = t & 15;
    const int m  = t >> 2, kc = t & 3;

    float acc[4][4];
#pragma unroll
    for (int i = 0; i < 4; ++i)
#pragma unroll
        for (int j = 0; j < 4; ++j) acc[i][j] = 0.f;

    for (int k0 = 0; k0 < K; k0 += 16) {
        float4 av = *(const float4*)(A  + (size_t)(bm + m) * K + k0 + kc * 4);
        float4 bv = *(const float4*)(Bw + (size_t)(bn + m) * K + k0 + kc * 4);
        As[kc*4+0][m] = av.x; As[kc*4+1][m] = av.y; As[kc*4+2][m] = av.z; As[kc*4+3][m] = av.w;
        Bs[kc*4+0][m] = bv.x; Bs[kc*4+1][m] = bv.y; Bs[kc*4+2][m] = bv.z; Bs[kc*4+3][m] = bv.w;
        __syncthreads();
#pragma unroll
        for (int k = 0; k < 16; ++k) {
            float a0 = As[k][tr*4+0], a1 = As[k][tr*4+1], a2 = As[k][tr*4+2], a3 = As[k][tr*4+3];
            float b0 = Bs[k][tc*4+0], b1 = Bs[k][tc*4+1], b2 = Bs[k][tc*4+2], b3 = Bs[k][tc*4+3];
            acc[0][0] += a0*b0; acc[0][1] += a0*b1; acc[0][2] += a0*b2; acc[0][3] += a0*b3;
            acc[1][0] += a1*b0; acc[1][1] += a1*b1; acc[1][2] += a1*b2; acc[1][3] += a1*b3;
            acc[2][0] += a2*b0; acc[2][1] += a2*b1; acc[2][2] += a2*b2; acc[2][3] += a2*b3;
            acc[3][0] += a3*b0; acc[3][1] += a3*b1; acc[3][2] += a3*b2; acc[3][3] += a3*b3;
        }
        __syncthreads();
    }
#pragma unroll
    for (int i = 0; i < 4; ++i) {
        int r = bm + tr * 4 + i;
#pragma unroll
        for (int j = 0; j < 4; ++j) {
            int c = bn + tc * 4 + j;
            float v = acc[i][j];
            if (bias) v += bias[c];
            if (relu) v = fmaxf(v, 0.f);
            C[(size_t)r * Nc + c] = v;
        }
    }
}

// ---------------------------------------------------------------------------
// a_src[n,h] = <hlin[n,h,:], att_src[h,:]>, same for dst. One thread per (n,h).
// ---------------------------------------------------------------------------
__global__ void att_proj(const float* __restrict__ hlin,
                         const float* __restrict__ att_s,
                         const float* __restrict__ att_d,
                         float* __restrict__ a_src, float* __restrict__ a_dst)
{
    int idx = blockIdx.x * 256 + threadIdx.x;
    if (idx >= NN * HH) return;
    int n = idx >> 3, h = idx & 7;
    const float* hp = hlin + (size_t)n * DD + h * HIDC;
    const float* as = att_s + h * HIDC;
    const float* ad = att_d + h * HIDC;
    float s1 = 0.f, s2 = 0.f;
#pragma unroll 8
    for (int c = 0; c < HIDC; ++c) { float hv = hp[c]; s1 += hv * as[c]; s2 += hv * ad[c]; }
    a_src[idx] = s1;
    a_dst[idx] = s2;
}

// ---------------------------------------------------------------------------
// CSR build: histogram over dst (incl. self-loops), scan, scatter src indices.
// ---------------------------------------------------------------------------
__global__ void hist_kernel(const int* __restrict__ ei, int* __restrict__ counts)
{
    int i = blockIdx.x * 256 + threadIdx.x;
    if (i >= ENE) return;
    int dst = (i < EE) ? ei[EE + i] : (i - EE);
    atomicAdd(&counts[dst], 1);
}

__global__ __launch_bounds__(1024) void scan_kernel(const int* __restrict__ counts,
                                                    int* __restrict__ offsets)
{
    __shared__ int sums[1024];
    int t = threadIdx.x;
    int v0 = counts[t*4+0], v1 = counts[t*4+1], v2 = counts[t*4+2], v3 = counts[t*4+3];
    sums[t] = v0 + v1 + v2 + v3;
    __syncthreads();
    for (int off = 1; off < 1024; off <<= 1) {
        int x = (t >= off) ? sums[t - off] : 0;
        __syncthreads();
        sums[t] += x;
        __syncthreads();
    }
    int pre = (t > 0) ? sums[t-1] : 0;
    offsets[t*4+0] = pre;
    offsets[t*4+1] = pre + v0;
    offsets[t*4+2] = pre + v0 + v1;
    offsets[t*4+3] = pre + v0 + v1 + v2;
    if (t == 1023) offsets[4096] = sums[1023];
}

__global__ void scatter_kernel(const int* __restrict__ ei, const int* __restrict__ offs,
                               int* __restrict__ cursor, int* __restrict__ src_sorted)
{
    int i = blockIdx.x * 256 + threadIdx.x;
    if (i >= ENE) return;
    int s, d;
    if (i < EE) { s = ei[i]; d = ei[EE + i]; } else { s = d = i - EE; }
    int pos = atomicAdd(&cursor[d], 1);
    src_sorted[offs[d] + pos] = s;
}

// ---------------------------------------------------------------------------
// GAT aggregation: one block (256 thr) per dst node. Two passes over incident
// edges: (1) per-head max of x=a_src+a_dst (lrelu monotone -> emax=lrelu(maxx)),
// (2) accumulate sum p*h_src and denom=sum p; out = acc/denom + bias.
// ---------------------------------------------------------------------------
__global__ __launch_bounds__(256) void gat_node(const float* __restrict__ hlin,
                                                const float* __restrict__ a_src,
                                                const float* __restrict__ a_dst,
                                                const int* __restrict__ offs,
                                                const int* __restrict__ src_sorted,
                                                const float* __restrict__ bias,
                                                float* __restrict__ out)
{
    __shared__ float adst[8];
    __shared__ float emax[8];
    __shared__ float denom[8];
    __shared__ float red[256];
    __shared__ float p_lds[16][8];
    __shared__ int   srcs[16];

    const int n = blockIdx.x, t = threadIdx.x;
    if (t < 8) { adst[t] = a_dst[n * 8 + t]; denom[t] = 0.f; }
    const int off0 = offs[n];
    const int deg  = offs[n+1] - off0;
    __syncthreads();

    // pass 1: per-head running max of x = a_src[s][h] + adst[h]
    const int h = t & 7, slot = t >> 3;
    float mx = -3.0e38f;
    for (int j = slot; j < deg; j += 32) {
        int s = src_sorted[off0 + j];
        mx = fmaxf(mx, a_src[s * 8 + h] + adst[h]);
    }
    red[t] = mx;
    __syncthreads();
    for (int half = 128; half >= 8; half >>= 1) {
        if (t < half) red[t] = fmaxf(red[t], red[t + half]);
        __syncthreads();
    }
    if (t < 8) emax[t] = lrelu02(red[t]);
    __syncthreads();

    // pass 2: accumulate
    float acc0 = 0.f, acc1 = 0.f;
    const int h0 = t >> 6, h1 = (t + 256) >> 6;
    for (int base = 0; base < deg; base += 16) {
        int cnt = min(16, deg - base);
        if (t < cnt * 8) {
            int j = base + (t >> 3);
            int s = src_sorted[off0 + j];
            if ((t & 7) == 0) srcs[t >> 3] = s;
            float x = a_src[s * 8 + (t & 7)] + adst[t & 7];
            float p = __expf(lrelu02(x) - emax[t & 7]);
            p_lds[t >> 3][t & 7] = p;
            atomicAdd(&denom[t & 7], p);
        }
        __syncthreads();
        for (int jj = 0; jj < cnt; ++jj) {
            int s = srcs[jj];
            const float* hp = hlin + (size_t)s * DD;
            acc0 += p_lds[jj][h0] * hp[t];
            acc1 += p_lds[jj][h1] * hp[256 + t];
        }
        __syncthreads();
    }
    out[(size_t)n * DD + t]       = acc0 / (denom[h0] + 1e-16f) + bias[t];
    out[(size_t)n * DD + 256 + t] = acc1 / (denom[h1] + 1e-16f) + bias[256 + t];
}

// ---------------------------------------------------------------------------
// Flash-style fp32 attention for one layer. Grid (N/64, H), 256 threads.
// Q tile 64x64 resident; loop K/V tiles of 64. Online softmax; PV via __shfl.
// qkv layout per row: [q(512) | k(512) | v(512)]; head h = cols h*64..h*64+63.
// ---------------------------------------------------------------------------
__global__ __launch_bounds__(256) void attn_fwd(const float* __restrict__ qkv,
                                                float* __restrict__ ao)
{
    __shared__ float Qs[64][65];
    __shared__ float Ks[64][65];
    __shared__ float Vs[64][65];
    const int qb = blockIdx.x, h = blockIdx.y;
    const int t = threadIdx.x, lane = t & 63;
    const int rg = t >> 4, cg = t & 15;

    for (int idx = t; idx < 1024; idx += 256) {
        int r = idx >> 4, kc = idx & 15;
        float4 v = *(const float4*)(qkv + (size_t)(qb*64 + r) * D3 + h * HIDC + kc * 4);
        Qs[r][kc*4+0] = v.x; Qs[r][kc*4+1] = v.y; Qs[r][kc*4+2] = v.z; Qs[r][kc*4+3] = v.w;
    }
    float O[4][4], m_run[4], l_run[4];
#pragma unroll
    for (int i = 0; i < 4; ++i) {
        m_run[i] = -3.0e38f; l_run[i] = 0.f;
#pragma unroll
        for (int j = 0; j < 4; ++j) O[i][j] = 0.f;
    }
    __syncthreads();

    for (int kb = 0; kb < NN / 64; ++kb) {
        for (int idx = t; idx < 1024; idx += 256) {
            int r = idx >> 4, kc = idx & 15;
            const float* kp = qkv + (size_t)(kb*64 + r) * D3 + DD + h * HIDC + kc * 4;
            float4 kv4 = *(const float4*)kp;
            float4 vv4 = *(const float4*)(kp + DD);
            Ks[r][kc*4+0] = kv4.x; Ks[r][kc*4+1] = kv4.y; Ks[r][kc*4+2] = kv4.z; Ks[r][kc*4+3] = kv4.w;
            Vs[r][kc*4+0] = vv4.x; Vs[r][kc*4+1] = vv4.y; Vs[r][kc*4+2] = vv4.z; Vs[r][kc*4+3] = vv4.w;
        }
        __syncthreads();

        float s[4][4];
#pragma unroll
        for (int i = 0; i < 4; ++i)
#pragma unroll
            for (int j = 0; j < 4; ++j) s[i][j] = 0.f;

#pragma unroll 8
        for (int k = 0; k < 64; ++k) {
            float q0 = Qs[rg*4+0][k], q1 = Qs[rg*4+1][k], q2 = Qs[rg*4+2][k], q3 = Qs[rg*4+3][k];
            float k0 = Ks[cg*4+0][k], k1 = Ks[cg*4+1][k], k2 = Ks[cg*4+2][k], k3 = Ks[cg*4+3][k];
            s[0][0] += q0*k0; s[0][1] += q0*k1; s[0][2] += q0*k2; s[0][3] += q0*k3;
            s[1][0] += q1*k0; s[1][1] += q1*k1; s[1][2] += q1*k2; s[1][3] += q1*k3;
            s[2][0] += q2*k0; s[2][1] += q2*k1; s[2][2] += q2*k2; s[2][3] += q2*k3;
            s[3][0] += q3*k0; s[3][1] += q3*k1; s[3][2] += q3*k2; s[3][3] += q3*k3;
        }

        float p[4][4];
#pragma unroll
        for (int i = 0; i < 4; ++i) {
#pragma unroll
            for (int j = 0; j < 4; ++j) s[i][j] *= 0.125f;
            float rm = fmaxf(fmaxf(s[i][0], s[i][1]), fmaxf(s[i][2], s[i][3]));
            rm = fmaxf(rm, __shfl_xor(rm, 1, 16));
            rm = fmaxf(rm, __shfl_xor(rm, 2, 16));
            rm = fmaxf(rm, __shfl_xor(rm, 4, 16));
            rm = fmaxf(rm, __shfl_xor(rm, 8, 16));
            float mn = fmaxf(m_run[i], rm);
            float f  = __expf(m_run[i] - mn);
            float psum = 0.f;
#pragma unroll
            for (int j = 0; j < 4; ++j) { p[i][j] = __expf(s[i][j] - mn); psum += p[i][j]; }
            psum += __shfl_xor(psum, 1, 16);
            psum += __shfl_xor(psum, 2, 16);
            psum += __shfl_xor(psum, 4, 16);
            psum += __shfl_xor(psum, 8, 16);
            l_run[i] = l_run[i] * f + psum;
            m_run[i] = mn;
#pragma unroll
            for (int j = 0; j < 4; ++j) O[i][j] *= f;
        }

        // PV: broadcast p across the 16 lanes of each row group via shfl
        for (int c4 = 0; c4 < 16; ++c4) {
            int src = (lane & 48) | c4;
#pragma unroll
            for (int jj = 0; jj < 4; ++jj) {
                int c = c4 * 4 + jj;
                float pb0 = __shfl(p[0][jj], src, 64);
                float pb1 = __shfl(p[1][jj], src, 64);
                float pb2 = __shfl(p[2][jj], src, 64);
                float pb3 = __shfl(p[3][jj], src, 64);
                float v0 = Vs[c][cg*4+0], v1 = Vs[c][cg*4+1], v2 = Vs[c][cg*4+2], v3 = Vs[c][cg*4+3];
                O[0][0] += pb0*v0; O[0][1] += pb0*v1; O[0][2] += pb0*v2; O[0][3] += pb0*v3;
                O[1][0] += pb1*v0; O[1][1] += pb1*v1; O[1][2] += pb1*v2; O[1][3] += pb1*v3;
                O[2][0] += pb2*v0; O[2][1] += pb2*v1; O[2][2] += pb2*v2; O[2][3] += pb2*v3;
                O[3][0] += pb3*v0; O[3][1] += pb3*v1; O[3][2] += pb3*v2; O[3][3] += pb3*v3;
            }
        }
        __syncthreads();
    }

#pragma unroll
    for (int i = 0; i < 4; ++i) {
        float inv = 1.f / l_run[i];
        size_t r = (size_t)(qb * 64 + rg * 4 + i);
#pragma unroll
        for (int j = 0; j < 4; ++j)
            ao[r * DD + h * HIDC + cg * 4 + j] = O[i][j] * inv;
    }
}

// ---------------------------------------------------------------------------
// Fused residual + LayerNorm: out = LN(hin + dlt) * g + b. One block per row.
// ---------------------------------------------------------------------------
__global__ __launch_bounds__(256) void ln_fused(const float* __restrict__ hin,
                                                const float* __restrict__ dlt,
                                                const float* __restrict__ g,
                                                const float* __restrict__ b,
                                                float* __restrict__ out)
{
    __shared__ float red[256];
    const int r = blockIdx.x, t = threadIdx.x;
    const size_t base = (size_t)r * DD;
    float v0 = hin[base + t] + dlt[base + t];
    float v1 = hin[base + 256 + t] + dlt[base + 256 + t];
    red[t] = v0 + v1;
    __syncthreads();
    for (int off = 128; off > 0; off >>= 1) { if (t < off) red[t] += red[t + off]; __syncthreads(); }
    float mu = red[0] * (1.f / 512.f);
    __syncthreads();
    float d0 = v0 - mu, d1 = v1 - mu;
    red[t] = d0 * d0 + d1 * d1;
    __syncthreads();
    for (int off = 128; off > 0; off >>= 1) { if (t < off) red[t] += red[t + off]; __syncthreads(); }
    float rs = rsqrtf(red[0] * (1.f / 512.f) + 1e-5f);
    out[base + t]       = d0 * rs * g[t] + b[t];
    out[base + 256 + t] = d1 * rs * g[256 + t] + b[256 + t];
}

// ---------------------------------------------------------------------------
extern "C" void kernel_launch(void* const* d_in, const int* in_sizes, int n_in,
                              void* d_out, int out_size, void* d_ws, size_t ws_size,
                              hipStream_t stream)
{
    (void)in_sizes; (void)n_in; (void)out_size; (void)ws_size;

    const float* x        = (const float*)d_in[0];
    const int*   ei       = (const int*)  d_in[1];
    const float* lin_w    = (const float*)d_in[3];
    const float* att_src  = (const float*)d_in[4];
    const float* att_dst  = (const float*)d_in[5];
    const float* gat_bias = (const float*)d_in[6];
    const float* qkv_w    = (const float*)d_in[7];
    const float* qkv_b    = (const float*)d_in[8];
    const float* out_w    = (const float*)d_in[9];
    const float* out_b    = (const float*)d_in[10];
    const float* ln1_g    = (const float*)d_in[11];
    const float* ln1_b    = (const float*)d_in[12];
    const float* ff1_w    = (const float*)d_in[13];
    const float* ff1_b    = (const float*)d_in[14];
    const float* ff2_w    = (const float*)d_in[15];
    const float* ff2_b    = (const float*)d_in[16];
    const float* ln2_g    = (const float*)d_in[17];
    const float* ln2_b    = (const float*)d_in[18];

    float* ws = (float*)d_ws;
    size_t o = 0;
    float* hlin   = ws + o; o += (size_t)NN * DD;     // GAT linear output
    float* hcur   = ws + o; o += (size_t)NN * DD;     // running hidden state
    float* qkvbuf = ws + o; o += (size_t)NN * D3;     // qkv (reused as o-proj out)
    float* ao     = ws + o; o += (size_t)NN * DD;     // attn heads out / ffn out
    float* ff1o   = ws + o; o += (size_t)NN * DFF2;   // ffn hidden
    float* a_src  = ws + o; o += (size_t)NN * HH;
    float* a_dst  = ws + o; o += (size_t)NN * HH;
    int* counts     = (int*)(ws + o); o += NN;
    int* cursor     = (int*)(ws + o); o += NN;
    int* offsets    = (int*)(ws + o); o += NN + 1;
    int* src_sorted = (int*)(ws + o); o += ENE;
    // total ~55.5 MB of workspace

    // --- GAT ---
    hipMemsetAsync(counts, 0, 2 * NN * sizeof(int), stream);  // counts + cursor
    gemm_bt<<<dim3(DD/64, NN/64), 256, 0, stream>>>(x, lin_w, nullptr, hlin, NN, IND, DD, 0);
    att_proj<<<(NN*HH + 255)/256, 256, 0, stream>>>(hlin, att_src, att_dst, a_src, a_dst);
    hist_kernel<<<(ENE + 255)/256, 256, 0, stream>>>(ei, counts);
    scan_kernel<<<1, 1024, 0, stream>>>(counts, offsets);
    scatter_kernel<<<(ENE + 255)/256, 256, 0, stream>>>(ei, offsets, cursor, src_sorted);
    gat_node<<<NN, 256, 0, stream>>>(hlin, a_src, a_dst, offsets, src_sorted, gat_bias, hcur);

    // --- 2 transformer encoder layers (post-norm) ---
    for (int i = 0; i < 2; ++i) {
        gemm_bt<<<dim3(D3/64, NN/64), 256, 0, stream>>>(hcur, qkv_w + (size_t)i*D3*DD,
                                                        qkv_b + (size_t)i*D3, qkvbuf, NN, DD, D3, 0);
        attn_fwd<<<dim3(NN/64, HH), 256, 0, stream>>>(qkvbuf, ao);
        gemm_bt<<<dim3(DD/64, NN/64), 256, 0, stream>>>(ao, out_w + (size_t)i*DD*DD,
                                                        out_b + (size_t)i*DD, qkvbuf, NN, DD, DD, 0);
        ln_fused<<<NN, 256, 0, stream>>>(hcur, qkvbuf, ln1_g + (size_t)i*DD, ln1_b + (size_t)i*DD, hcur);
        gemm_bt<<<dim3(DFF2/64, NN/64), 256, 0, stream>>>(hcur, ff1_w + (size_t)i*DFF2*DD,
                                                          ff1_b + (size_t)i*DFF2, ff1o, NN, DD, DFF2, 1);
        gemm_bt<<<dim3(DD/64, NN/64), 256, 0, stream>>>(ff1o, ff2_w + (size_t)i*DD*DFF2,
                                                        ff2_b + (size_t)i*DD, ao, NN, DFF2, DD, 0);
        float* outp = (i == 1) ? (float*)d_out : hcur;
        ln_fused<<<NN, 256, 0, stream>>>(hcur, ao, ln2_g + (size_t)i*DD, ln2_b + (size_t)i*DD, outp);
    }
}

// Round 2
// 818.825 us; speedup vs baseline: 3.0100x; 3.0100x over previous
//
#include <hip/hip_runtime.h>
#include <math.h>

// Problem constants (match reference)
#define NN    4096
#define EE    131072
#define ENE   (EE + NN)      // edges + self loops = 135168
#define IND   128
#define HH    8
#define HIDC  64
#define DD    512
#define D3    1536
#define DFF2  256

typedef __attribute__((ext_vector_type(8))) short short8;
typedef __attribute__((ext_vector_type(4))) float f32x4;
typedef __attribute__((ext_vector_type(2))) unsigned int uint2v;

__device__ __forceinline__ float lrelu02(float x) { return x >= 0.f ? x : 0.2f * x; }

// round-to-nearest-even f32 -> bf16 bits (inputs finite)
__device__ __forceinline__ unsigned short f2bf(float x) {
    unsigned int u = __float_as_uint(x);
    u += 0x7fffu + ((u >> 16) & 1u);
    return (unsigned short)(u >> 16);
}

// ---------------------------------------------------------------------------
// Generic C[M,Nc] = A[M,K] @ Bw[Nc,K]^T (+bias, optional relu). fp32.
// ---------------------------------------------------------------------------
__global__ __launch_bounds__(256) void gemm_bt(const float* __restrict__ A,
                                               const float* __restrict__ Bw,
                                               const float* __restrict__ bias,
                                               float* __restrict__ C,
                                               int M, int K, int Nc, int relu)
{
    __shared__ float As[16][65];
    __shared__ float Bs[16][65];
    const int t  = threadIdx.x;
    const int bm = blockIdx.y * 64, bn = blockIdx.x * 64;
    const int tr = t >> 4, tc = t & 15;
    const int m  = t >> 2, kc = t & 3;

    float acc[4][4];
#pragma unroll
    for (int i = 0; i < 4; ++i)
#pragma unroll
        for (int j = 0; j < 4; ++j) acc[i][j] = 0.f;

    for (int k0 = 0; k0 < K; k0 += 16) {
        float4 av = *(const float4*)(A  + (size_t)(bm + m) * K + k0 + kc * 4);
        float4 bv = *(const float4*)(Bw + (size_t)(bn + m) * K + k0 + kc * 4);
        As[kc*4+0][m] = av.x; As[kc*4+1][m] = av.y; As[kc*4+2][m] = av.z; As[kc*4+3][m] = av.w;
        Bs[kc*4+0][m] = bv.x; Bs[kc*4+1][m] = bv.y; Bs[kc*4+2][m] = bv.z; Bs[kc*4+3][m] = bv.w;
        __syncthreads();
#pragma unroll
        for (int k = 0; k < 16; ++k) {
            float a0 = As[k][tr*4+0], a1 = As[k][tr*4+1], a2 = As[k][tr*4+2], a3 = As[k][tr*4+3];
            float b0 = Bs[k][tc*4+0], b1 = Bs[k][tc*4+1], b2 = Bs[k][tc*4+2], b3 = Bs[k][tc*4+3];
            acc[0][0] += a0*b0; acc[0][1] += a0*b1; acc[0][2] += a0*b2; acc[0][3] += a0*b3;
            acc[1][0] += a1*b0; acc[1][1] += a1*b1; acc[1][2] += a1*b2; acc[1][3] += a1*b3;
            acc[2][0] += a2*b0; acc[2][1] += a2*b1; acc[2][2] += a2*b2; acc[2][3] += a2*b3;
            acc[3][0] += a3*b0; acc[3][1] += a3*b1; acc[3][2] += a3*b2; acc[3][3] += a3*b3;
        }
        __syncthreads();
    }
#pragma unroll
    for (int i = 0; i < 4; ++i) {
        int r = bm + tr * 4 + i;
#pragma unroll
        for (int j = 0; j < 4; ++j) {
            int c = bn + tc * 4 + j;
            float v = acc[i][j];
            if (bias) v += bias[c];
            if (relu) v = fmaxf(v, 0.f);
            C[(size_t)r * Nc + c] = v;
        }
    }
}

// ---------------------------------------------------------------------------
// QKV GEMM variant: fp32 compute, bf16 output; cols < DD (the Q part) scaled
// by 1/sqrt(64) so attention needs no score scaling.
// ---------------------------------------------------------------------------
__global__ __launch_bounds__(256) void gemm_bt_qkv(const float* __restrict__ A,
                                                   const float* __restrict__ Bw,
                                                   const float* __restrict__ bias,
                                                   unsigned short* __restrict__ C,
                                                   int M, int K, int Nc)
{
    __shared__ float As[16][65];
    __shared__ float Bs[16][65];
    const int t  = threadIdx.x;
    const int bm = blockIdx.y * 64, bn = blockIdx.x * 64;
    const int tr = t >> 4, tc = t & 15;
    const int m  = t >> 2, kc = t & 3;

    float acc[4][4];
#pragma unroll
    for (int i = 0; i < 4; ++i)
#pragma unroll
        for (int j = 0; j < 4; ++j) acc[i][j] = 0.f;

    for (int k0 = 0; k0 < K; k0 += 16) {
        float4 av = *(const float4*)(A  + (size_t)(bm + m) * K + k0 + kc * 4);
        float4 bv = *(const float4*)(Bw + (size_t)(bn + m) * K + k0 + kc * 4);
        As[kc*4+0][m] = av.x; As[kc*4+1][m] = av.y; As[kc*4+2][m] = av.z; As[kc*4+3][m] = av.w;
        Bs[kc*4+0][m] = bv.x; Bs[kc*4+1][m] = bv.y; Bs[kc*4+2][m] = bv.z; Bs[kc*4+3][m] = bv.w;
        __syncthreads();
#pragma unroll
        for (int k = 0; k < 16; ++k) {
            float a0 = As[k][tr*4+0], a1 = As[k][tr*4+1], a2 = As[k][tr*4+2], a3 = As[k][tr*4+3];
            float b0 = Bs[k][tc*4+0], b1 = Bs[k][tc*4+1], b2 = Bs[k][tc*4+2], b3 = Bs[k][tc*4+3];
            acc[0][0] += a0*b0; acc[0][1] += a0*b1; acc[0][2] += a0*b2; acc[0][3] += a0*b3;
            acc[1][0] += a1*b0; acc[1][1] += a1*b1; acc[1][2] += a1*b2; acc[1][3] += a1*b3;
            acc[2][0] += a2*b0; acc[2][1] += a2*b1; acc[2][2] += a2*b2; acc[2][3] += a2*b3;
            acc[3][0] += a3*b0; acc[3][1] += a3*b1; acc[3][2] += a3*b2; acc[3][3] += a3*b3;
        }
        __syncthreads();
    }
#pragma unroll
    for (int i = 0; i < 4; ++i) {
        int r = bm + tr * 4 + i;
#pragma unroll
        for (int j = 0; j < 4; ++j) {
            int c = bn + tc * 4 + j;
            float v = acc[i][j] + bias[c];
            if (c < DD) v *= 0.125f;            // fold 1/sqrt(HIDC) into Q
            C[(size_t)r * Nc + c] = f2bf(v);
        }
    }
}

// ---------------------------------------------------------------------------
// a_src[n,h] = <hlin[n,h,:], att_src[h,:]>, same for dst.
// ---------------------------------------------------------------------------
__global__ void att_proj(const float* __restrict__ hlin,
                         const float* __restrict__ att_s,
                         const float* __restrict__ att_d,
                         float* __restrict__ a_src, float* __restrict__ a_dst)
{
    int idx = blockIdx.x * 256 + threadIdx.x;
    if (idx >= NN * HH) return;
    int n = idx >> 3, h = idx & 7;
    const float* hp = hlin + (size_t)n * DD + h * HIDC;
    const float* as = att_s + h * HIDC;
    const float* ad = att_d + h * HIDC;
    float s1 = 0.f, s2 = 0.f;
#pragma unroll 8
    for (int c = 0; c < HIDC; ++c) { float hv = hp[c]; s1 += hv * as[c]; s2 += hv * ad[c]; }
    a_src[idx] = s1;
    a_dst[idx] = s2;
}

// ---------------------------------------------------------------------------
// CSR build: histogram over dst (incl. self-loops), scan, scatter src indices.
// ---------------------------------------------------------------------------
__global__ void hist_kernel(const int* __restrict__ ei, int* __restrict__ counts)
{
    int i = blockIdx.x * 256 + threadIdx.x;
    if (i >= ENE) return;
    int dst = (i < EE) ? ei[EE + i] : (i - EE);
    atomicAdd(&counts[dst], 1);
}

__global__ __launch_bounds__(1024) void scan_kernel(const int* __restrict__ counts,
                                                    int* __restrict__ offsets)
{
    __shared__ int sums[1024];
    int t = threadIdx.x;
    int v0 = counts[t*4+0], v1 = counts[t*4+1], v2 = counts[t*4+2], v3 = counts[t*4+3];
    sums[t] = v0 + v1 + v2 + v3;
    __syncthreads();
    for (int off = 1; off < 1024; off <<= 1) {
        int x = (t >= off) ? sums[t - off] : 0;
        __syncthreads();
        sums[t] += x;
        __syncthreads();
    }
    int pre = (t > 0) ? sums[t-1] : 0;
    offsets[t*4+0] = pre;
    offsets[t*4+1] = pre + v0;
    offsets[t*4+2] = pre + v0 + v1;
    offsets[t*4+3] = pre + v0 + v1 + v2;
    if (t == 1023) offsets[4096] = sums[1023];
}

__global__ void scatter_kernel(const int* __restrict__ ei, const int* __restrict__ offs,
                               int* __restrict__ cursor, int* __restrict__ src_sorted)
{
    int i = blockIdx.x * 256 + threadIdx.x;
    if (i >= ENE) return;
    int s, d;
    if (i < EE) { s = ei[i]; d = ei[EE + i]; } else { s = d = i - EE; }
    int pos = atomicAdd(&cursor[d], 1);
    src_sorted[offs[d] + pos] = s;
}

// ---------------------------------------------------------------------------
// GAT aggregation: one block per dst node (unchanged from round 1).
// ---------------------------------------------------------------------------
__global__ __launch_bounds__(256) void gat_node(const float* __restrict__ hlin,
                                                const float* __restrict__ a_src,
                                                const float* __restrict__ a_dst,
                                                const int* __restrict__ offs,
                                                const int* __restrict__ src_sorted,
                                                const float* __restrict__ bias,
                                                float* __restrict__ out)
{
    __shared__ float adst[8];
    __shared__ float emax[8];
    __shared__ float denom[8];
    __shared__ float red[256];
    __shared__ float p_lds[16][8];
    __shared__ int   srcs[16];

    const int n = blockIdx.x, t = threadIdx.x;
    if (t < 8) { adst[t] = a_dst[n * 8 + t]; denom[t] = 0.f; }
    const int off0 = offs[n];
    const int deg  = offs[n+1] - off0;
    __syncthreads();

    const int h = t & 7, slot = t >> 3;
    float mx = -3.0e38f;
    for (int j = slot; j < deg; j += 32) {
        int s = src_sorted[off0 + j];
        mx = fmaxf(mx, a_src[s * 8 + h] + adst[h]);
    }
    red[t] = mx;
    __syncthreads();
    for (int half = 128; half >= 8; half >>= 1) {
        if (t < half) red[t] = fmaxf(red[t], red[t + half]);
        __syncthreads();
    }
    if (t < 8) emax[t] = lrelu02(red[t]);
    __syncthreads();

    float acc0 = 0.f, acc1 = 0.f;
    const int h0 = t >> 6, h1 = (t + 256) >> 6;
    for (int base = 0; base < deg; base += 16) {
        int cnt = min(16, deg - base);
        if (t < cnt * 8) {
            int j = base + (t >> 3);
            int s = src_sorted[off0 + j];
            if ((t & 7) == 0) srcs[t >> 3] = s;
            float x = a_src[s * 8 + (t & 7)] + adst[t & 7];
            float p = __expf(lrelu02(x) - emax[t & 7]);
            p_lds[t >> 3][t & 7] = p;
            atomicAdd(&denom[t & 7], p);
        }
        __syncthreads();
        for (int jj = 0; jj < cnt; ++jj) {
            int s = srcs[jj];
            const float* hp = hlin + (size_t)s * DD;
            acc0 += p_lds[jj][h0] * hp[t];
            acc1 += p_lds[jj][h1] * hp[256 + t];
        }
        __syncthreads();
    }
    out[(size_t)n * DD + t]       = acc0 / (denom[h0] + 1e-16f) + bias[t];
    out[(size_t)n * DD + 256 + t] = acc1 / (denom[h1] + 1e-16f) + bias[256 + t];
}

// ---------------------------------------------------------------------------
// bf16 MFMA flash attention. Grid (NN/64, HH), 256 threads = 4 waves.
// Wave owns 16 Q rows. KV tiles of 64. Swapped QK^T (mfma(K,Q) -> S^T with
// q = lane&15) => softmax stats lane-local after 2 shfl_xor; P packed to
// row-major bf16 LDS via 8B writes; PV swapped (mfma(Vt,P) -> O^T, q stays
// on lane&15 so rescale/epilogue need no shuffles). K/Vt/P XOR-swizzled:
// idx ^= (row&7)<<3 (shorts) on BOTH write and read (G4 / rule #21).
// ---------------------------------------------------------------------------
__global__ __launch_bounds__(256) void attn_mfma(const unsigned short* __restrict__ qkv,
                                                 float* __restrict__ ao)
{
    __shared__ __align__(16) unsigned short Ks[64 * 64];
    __shared__ __align__(16) unsigned short Vt[64 * 64];
    __shared__ __align__(16) unsigned short Ps[4 * 16 * 64];

    const int t = threadIdx.x;
    const int w = t >> 6, lane = t & 63;
    const int q15 = lane & 15, g = lane >> 4;
    const int h = blockIdx.y;
    const int qbase = blockIdx.x * 64 + w * 16;

    // Q fragments (bf16 global; 0.125 pre-folded by gemm_bt_qkv)
    const unsigned short* qrow = qkv + (size_t)(qbase + q15) * D3 + h * HIDC;
    const short8 qf0 = *(const short8*)(qrow + g * 8);
    const short8 qf1 = *(const short8*)(qrow + 32 + g * 8);

    f32x4 O[4];
#pragma unroll
    for (int db = 0; db < 4; ++db) O[db] = (f32x4){0.f, 0.f, 0.f, 0.f};
    float m_run = -3.0e38f, l_run = 0.f;

    // staging assignments
    const int r0 = t >> 3, ch = t & 7;   // K: rows r0 and r0+32, 8-col chunk ch
    const int kp = t & 31, dg = t >> 5;  // Vt: k-pair kp, d-group dg

    for (int kb = 0; kb < NN / 64; ++kb) {
        const int kbase = kb * 64;
        {   // stage K tile (row-major, swizzled)
            const unsigned short* kg = qkv + (size_t)(kbase + r0) * D3 + DD + h * HIDC + ch * 8;
            short8 k0 = *(const short8*)kg;
            short8 k1 = *(const short8*)(kg + (size_t)32 * D3);
            *(short8*)&Ks[(r0 * 64 + ch * 8) ^ ((r0 & 7) << 3)] = k0;
            const int r1 = r0 + 32;
            *(short8*)&Ks[(r1 * 64 + ch * 8) ^ ((r1 & 7) << 3)] = k1;
        }
        {   // stage V transposed: Vt[d][k], pack k-pairs into b32 writes
            const unsigned short* vg = qkv + (size_t)(kbase + 2 * kp) * D3 + 2 * DD + h * HIDC + dg * 8;
            short8 v0 = *(const short8*)vg;
            short8 v1 = *(const short8*)(vg + D3);
#pragma unroll
            for (int i = 0; i < 8; ++i) {
                unsigned int pk = (unsigned int)(unsigned short)v0[i]
                                | ((unsigned int)(unsigned short)v1[i] << 16);
                int d = dg * 8 + i;
                *(unsigned int*)&Vt[(d * 64 + 2 * kp) ^ ((d & 7) << 3)] = pk;
            }
        }
        __syncthreads();

        // QK^T swapped: St[kv][q], D col = lane&15 = q
        f32x4 st[4];
#pragma unroll
        for (int kvb = 0; kvb < 4; ++kvb) {
            const int kr = kvb * 16 + q15;
            const short8 kf0 = *(const short8*)&Ks[(kr * 64 + g * 8) ^ ((kr & 7) << 3)];
            const short8 kf1 = *(const short8*)&Ks[(kr * 64 + 32 + g * 8) ^ ((kr & 7) << 3)];
            f32x4 acc = (f32x4){0.f, 0.f, 0.f, 0.f};
            acc = __builtin_amdgcn_mfma_f32_16x16x32_bf16(kf0, qf0, acc, 0, 0, 0);
            acc = __builtin_amdgcn_mfma_f32_16x16x32_bf16(kf1, qf1, acc, 0, 0, 0);
            st[kvb] = acc;
        }

        // online softmax; row stats for q = lane&15 (lanes l, l^16, l^32, l^48 share q)
        float mx = -3.0e38f;
#pragma unroll
        for (int kvb = 0; kvb < 4; ++kvb)
#pragma unroll
            for (int r = 0; r < 4; ++r) mx = fmaxf(mx, st[kvb][r]);
        mx = fmaxf(mx, __shfl_xor(mx, 16, 64));
        mx = fmaxf(mx, __shfl_xor(mx, 32, 64));
        const float mnew = fmaxf(m_run, mx);
        const float f = __expf(m_run - mnew);
        float p[16];
        float ls = 0.f;
#pragma unroll
        for (int kvb = 0; kvb < 4; ++kvb)
#pragma unroll
            for (int r = 0; r < 4; ++r) {
                float e = __expf(st[kvb][r] - mnew);
                p[kvb * 4 + r] = e;
                ls += e;
            }
        ls += __shfl_xor(ls, 16, 64);
        ls += __shfl_xor(ls, 32, 64);
        l_run = l_run * f + ls;
        m_run = mnew;
#pragma unroll
        for (int db = 0; db < 4; ++db) O[db] *= f;

        // pack P -> per-wave row-major LDS (q = lane&15 row, kv cols), swizzled
        unsigned short* pw = &Ps[w * (16 * 64)];
#pragma unroll
        for (int kvb = 0; kvb < 4; ++kvb) {
            uint2v pk;
            pk.x = (unsigned int)f2bf(p[kvb * 4 + 0]) | ((unsigned int)f2bf(p[kvb * 4 + 1]) << 16);
            pk.y = (unsigned int)f2bf(p[kvb * 4 + 2]) | ((unsigned int)f2bf(p[kvb * 4 + 3]) << 16);
            const int col = kvb * 16 + g * 4;
            *(uint2v*)&pw[(q15 * 64 + col) ^ ((q15 & 7) << 3)] = pk;
        }
        // read P back as B-fragments (within-wave RAW; compiler emits lgkmcnt)
        const short8 pf0 = *(const short8*)&pw[(q15 * 64 + g * 8) ^ ((q15 & 7) << 3)];
        const short8 pf1 = *(const short8*)&pw[(q15 * 64 + 32 + g * 8) ^ ((q15 & 7) << 3)];

        // PV swapped: O^T[d][q] += Vt @ P^T ; D col = lane&15 = q (matches f, l)
#pragma unroll
        for (int db = 0; db < 4; ++db) {
            const int vr = db * 16 + q15;
            const short8 vf0 = *(const short8*)&Vt[(vr * 64 + g * 8) ^ ((vr & 7) << 3)];
            const short8 vf1 = *(const short8*)&Vt[(vr * 64 + 32 + g * 8) ^ ((vr & 7) << 3)];
            O[db] = __builtin_amdgcn_mfma_f32_16x16x32_bf16(vf0, pf0, O[db], 0, 0, 0);
            O[db] = __builtin_amdgcn_mfma_f32_16x16x32_bf16(vf1, pf1, O[db], 0, 0, 0);
        }
        __syncthreads();   // all waves done with Ks/Vt before next stage
    }

    const float linv = 1.f / l_run;
#pragma unroll
    for (int db = 0; db < 4; ++db) {
        float4 o;
        o.x = O[db][0] * linv; o.y = O[db][1] * linv;
        o.z = O[db][2] * linv; o.w = O[db][3] * linv;
        // O^T: d = db*16 + g*4 + reg, q = qbase + q15
        *(float4*)&ao[(size_t)(qbase + q15) * DD + h * HIDC + db * 16 + g * 4] = o;
    }
}

// ---------------------------------------------------------------------------
// Fused residual + LayerNorm: out = LN(hin + dlt) * g + b. One block per row.
// ---------------------------------------------------------------------------
__global__ __launch_bounds__(256) void ln_fused(const float* __restrict__ hin,
                                                const float* __restrict__ dlt,
                                                const float* __restrict__ g,
                                                const float* __restrict__ b,
                                                float* __restrict__ out)
{
    __shared__ float red[256];
    const int r = blockIdx.x, t = threadIdx.x;
    const size_t base = (size_t)r * DD;
    float v0 = hin[base + t] + dlt[base + t];
    float v1 = hin[base + 256 + t] + dlt[base + 256 + t];
    red[t] = v0 + v1;
    __syncthreads();
    for (int off = 128; off > 0; off >>= 1) { if (t < off) red[t] += red[t + off]; __syncthreads(); }
    float mu = red[0] * (1.f / 512.f);
    __syncthreads();
    float d0 = v0 - mu, d1 = v1 - mu;
    red[t] = d0 * d0 + d1 * d1;
    __syncthreads();
    for (int off = 128; off > 0; off >>= 1) { if (t < off) red[t] += red[t + off]; __syncthreads(); }
    float rs = rsqrtf(red[0] * (1.f / 512.f) + 1e-5f);
    out[base + t]       = d0 * rs * g[t] + b[t];
    out[base + 256 + t] = d1 * rs * g[256 + t] + b[256 + t];
}

// ---------------------------------------------------------------------------
extern "C" void kernel_launch(void* const* d_in, const int* in_sizes, int n_in,
                              void* d_out, int out_size, void* d_ws, size_t ws_size,
                              hipStream_t stream)
{
    (void)in_sizes; (void)n_in; (void)out_size; (void)ws_size;

    const float* x        = (const float*)d_in[0];
    const int*   ei       = (const int*)  d_in[1];
    const float* lin_w    = (const float*)d_in[3];
    const float* att_src  = (const float*)d_in[4];
    const float* att_dst  = (const float*)d_in[5];
    const float* gat_bias = (const float*)d_in[6];
    const float* qkv_w    = (const float*)d_in[7];
    const float* qkv_b    = (const float*)d_in[8];
    const float* out_w    = (const float*)d_in[9];
    const float* out_b    = (const float*)d_in[10];
    const float* ln1_g    = (const float*)d_in[11];
    const float* ln1_b    = (const float*)d_in[12];
    const float* ff1_w    = (const float*)d_in[13];
    const float* ff1_b    = (const float*)d_in[14];
    const float* ff2_w    = (const float*)d_in[15];
    const float* ff2_b    = (const float*)d_in[16];
    const float* ln2_g    = (const float*)d_in[17];
    const float* ln2_b    = (const float*)d_in[18];

    float* ws = (float*)d_ws;
    size_t o = 0;
    float* hlin   = ws + o; o += (size_t)NN * DD;
    float* hcur   = ws + o; o += (size_t)NN * DD;
    float* qkvbuf = ws + o; o += (size_t)NN * D3;     // bf16 qkv lives here; later reused fp32 for o-proj out
    float* ao     = ws + o; o += (size_t)NN * DD;
    float* ff1o   = ws + o; o += (size_t)NN * DFF2;
    float* a_src  = ws + o; o += (size_t)NN * HH;
    float* a_dst  = ws + o; o += (size_t)NN * HH;
    int* counts     = (int*)(ws + o); o += NN;
    int* cursor     = (int*)(ws + o); o += NN;
    int* offsets    = (int*)(ws + o); o += NN + 1;
    int* src_sorted = (int*)(ws + o); o += ENE;

    // --- GAT ---
    hipMemsetAsync(counts, 0, 2 * NN * sizeof(int), stream);  // counts + cursor
    gemm_bt<<<dim3(DD/64, NN/64), 256, 0, stream>>>(x, lin_w, nullptr, hlin, NN, IND, DD, 0);
    att_proj<<<(NN*HH + 255)/256, 256, 0, stream>>>(hlin, att_src, att_dst, a_src, a_dst);
    hist_kernel<<<(ENE + 255)/256, 256, 0, stream>>>(ei, counts);
    scan_kernel<<<1, 1024, 0, stream>>>(counts, offsets);
    scatter_kernel<<<(ENE + 255)/256, 256, 0, stream>>>(ei, offsets, cursor, src_sorted);
    gat_node<<<NN, 256, 0, stream>>>(hlin, a_src, a_dst, offsets, src_sorted, gat_bias, hcur);

    // --- 2 transformer encoder layers (post-norm) ---
    unsigned short* qkv16 = (unsigned short*)qkvbuf;
    for (int i = 0; i < 2; ++i) {
        gemm_bt_qkv<<<dim3(D3/64, NN/64), 256, 0, stream>>>(hcur, qkv_w + (size_t)i*D3*DD,
                                                            qkv_b + (size_t)i*D3, qkv16, NN, DD, D3);
        attn_mfma<<<dim3(NN/64, HH), 256, 0, stream>>>(qkv16, ao);
        gemm_bt<<<dim3(DD/64, NN/64), 256, 0, stream>>>(ao, out_w + (size_t)i*DD*DD,
                                                        out_b + (size_t)i*DD, qkvbuf, NN, DD, DD, 0);
        ln_fused<<<NN, 256, 0, stream>>>(hcur, qkvbuf, ln1_g + (size_t)i*DD, ln1_b + (size_t)i*DD, hcur);
        gemm_bt<<<dim3(DFF2/64, NN/64), 256, 0, stream>>>(hcur, ff1_w + (size_t)i*DFF2*DD,
                                                          ff1_b + (size_t)i*DFF2, ff1o, NN, DD, DFF2, 1);
        gemm_bt<<<dim3(DD/64, NN/64), 256, 0, stream>>>(ff1o, ff2_w + (size_t)i*DD*DFF2,
                                                        ff2_b + (size_t)i*DD, ao, NN, DFF2, DD, 0);
        float* outp = (i == 1) ? (float*)d_out : hcur;
        ln_fused<<<NN, 256, 0, stream>>>(hcur, ao, ln2_g + (size_t)i*DD, ln2_b + (size_t)i*DD, outp);
    }
}

// Round 3
// 453.957 us; speedup vs baseline: 5.4293x; 1.8038x over previous
//
#include <hip/hip_runtime.h>
#include <math.h>

// Problem constants (match reference)
#define NN    4096
#define EE    131072
#define ENE   (EE + NN)      // edges + self loops = 135168
#define IND   128
#define HH    8
#define HIDC  64
#define DD    512
#define D3    1536
#define DFF2  256

typedef __attribute__((ext_vector_type(8))) short short8;
typedef __attribute__((ext_vector_type(4))) float f32x4;
typedef __attribute__((ext_vector_type(2))) unsigned int uint2v;

__device__ __forceinline__ float lrelu02(float x) { return x >= 0.f ? x : 0.2f * x; }

// round-to-nearest-even f32 -> bf16 bits (inputs finite)
__device__ __forceinline__ unsigned short f2bf(float x) {
    unsigned int u = __float_as_uint(x);
    u += 0x7fffu + ((u >> 16) & 1u);
    return (unsigned short)(u >> 16);
}
__device__ __forceinline__ float bf2f(unsigned short u) {
    return __uint_as_float((unsigned int)u << 16);
}

// ---------------------------------------------------------------------------
// Batched fp32 -> bf16 conversion (weights + x), one launch, 6 segments.
// ---------------------------------------------------------------------------
struct CvtJobs {
    const float* src[6];
    unsigned short* dst[6];
    int n[6];
};

__global__ __launch_bounds__(256) void cvt_many(CvtJobs jb, int total)
{
    int i = (blockIdx.x * 256 + threadIdx.x) * 4;
    if (i >= total) return;
    int s = 0;
    while (i >= jb.n[s]) { i -= jb.n[s]; ++s; }
    float4 v = *(const float4*)(jb.src[s] + i);
    unsigned int lo = (unsigned int)f2bf(v.x) | ((unsigned int)f2bf(v.y) << 16);
    unsigned int hi = (unsigned int)f2bf(v.z) | ((unsigned int)f2bf(v.w) << 16);
    uint2v pk; pk.x = lo; pk.y = hi;
    *(uint2v*)(jb.dst[s] + i) = pk;
}

// ---------------------------------------------------------------------------
// bf16 MFMA GEMM: C[M,N] = A[M,K] @ W[N,K]^T (+bias). 128x128 tile, BK=64,
// 4 waves (2x2), 4x4 16x16x32 fragments per wave. Reg-staged LDS with XOR
// swizzle (chunk ^= row&7) on BOTH write and read (G4 / rule #21).
// flags: bit0 = bf16 out, bit1 = relu, bit2 = scale cols<512 by 0.125 (QKV).
// Requires M%128==0, N%128==0, K%64==0.
// ---------------------------------------------------------------------------
__global__ __launch_bounds__(256) void gemm_bf16(const unsigned short* __restrict__ A,
                                                 const unsigned short* __restrict__ W,
                                                 const float* __restrict__ bias,
                                                 void* __restrict__ C,
                                                 int M, int K, int N, int flags)
{
    __shared__ __align__(16) unsigned short As[128 * 64];
    __shared__ __align__(16) unsigned short Bs[128 * 64];

    const int t = threadIdx.x, lane = t & 63, w = t >> 6;
    const int wr = w >> 1, wc = w & 1;
    const int bm = blockIdx.y * 128, bn = blockIdx.x * 128;
    const int q = lane & 15, g = lane >> 4;

    f32x4 acc[4][4];
#pragma unroll
    for (int m = 0; m < 4; ++m)
#pragma unroll
        for (int n = 0; n < 4; ++n) acc[m][n] = (f32x4){0.f, 0.f, 0.f, 0.f};

    // staging: 2 threads per row, each 32 bf16 (4 x short8)
    const int srow = t >> 1, sh = t & 1;
    const unsigned short* Ag = A + (size_t)(bm + srow) * K + sh * 32;
    const unsigned short* Wg = W + (size_t)(bn + srow) * K + sh * 32;
    // swizzled LDS write byte offsets for chunks c = sh*4 + i
    int wofs[4];
#pragma unroll
    for (int i = 0; i < 4; ++i)
        wofs[i] = srow * 128 + ((((sh * 4 + i) * 16) ^ ((srow & 7) << 4)));

    for (int k0 = 0; k0 < K; k0 += 64) {
        short8 av[4], bv[4];
#pragma unroll
        for (int i = 0; i < 4; ++i) {
            av[i] = *(const short8*)(Ag + k0 + i * 8);
            bv[i] = *(const short8*)(Wg + k0 + i * 8);
        }
        __syncthreads();   // previous tile's reads complete
#pragma unroll
        for (int i = 0; i < 4; ++i) {
            *(short8*)((char*)As + wofs[i]) = av[i];
            *(short8*)((char*)Bs + wofs[i]) = bv[i];
        }
        __syncthreads();

        short8 af[2][4], bfr[2][4];
#pragma unroll
        for (int m = 0; m < 4; ++m) {
            const int row = wr * 64 + m * 16 + q;
#pragma unroll
            for (int kk = 0; kk < 2; ++kk)
                af[kk][m] = *(const short8*)((const char*)As +
                    row * 128 + ((((kk * 4 + g) * 16) ^ ((row & 7) << 4))));
        }
#pragma unroll
        for (int n = 0; n < 4; ++n) {
            const int row = wc * 64 + n * 16 + q;
#pragma unroll
            for (int kk = 0; kk < 2; ++kk)
                bfr[kk][n] = *(const short8*)((const char*)Bs +
                    row * 128 + ((((kk * 4 + g) * 16) ^ ((row & 7) << 4))));
        }
#pragma unroll
        for (int kk = 0; kk < 2; ++kk)
#pragma unroll
            for (int m = 0; m < 4; ++m)
#pragma unroll
                for (int n = 0; n < 4; ++n)
                    acc[m][n] = __builtin_amdgcn_mfma_f32_16x16x32_bf16(
                        bfr[kk][n], af[kk][m], acc[m][n], 0, 0, 0);
    }

    // epilogue: lane holds C[bm+wr*64+m*16+q][bn+wc*64+n*16+g*4 + r], r=0..3
    const int obf = flags & 1, orelu = flags & 2, oqs = flags & 4;
#pragma unroll
    for (int m = 0; m < 4; ++m) {
        const int row = bm + wr * 64 + m * 16 + q;
#pragma unroll
        for (int n = 0; n < 4; ++n) {
            const int col0 = bn + wc * 64 + n * 16 + g * 4;
            f32x4 v = acc[m][n];
            if (bias) {
                float4 bv4 = *(const float4*)(bias + col0);
                v[0] += bv4.x; v[1] += bv4.y; v[2] += bv4.z; v[3] += bv4.w;
            }
            if (oqs && col0 < DD) {
                v[0] *= 0.125f; v[1] *= 0.125f; v[2] *= 0.125f; v[3] *= 0.125f;
            }
            if (orelu) {
                v[0] = fmaxf(v[0], 0.f); v[1] = fmaxf(v[1], 0.f);
                v[2] = fmaxf(v[2], 0.f); v[3] = fmaxf(v[3], 0.f);
            }
            if (obf) {
                uint2v pk;
                pk.x = (unsigned int)f2bf(v[0]) | ((unsigned int)f2bf(v[1]) << 16);
                pk.y = (unsigned int)f2bf(v[2]) | ((unsigned int)f2bf(v[3]) << 16);
                *(uint2v*)((unsigned short*)C + (size_t)row * N + col0) = pk;
            } else {
                float4 o; o.x = v[0]; o.y = v[1]; o.z = v[2]; o.w = v[3];
                *(float4*)((float*)C + (size_t)row * N + col0) = o;
            }
        }
    }
}

// ---------------------------------------------------------------------------
// a_src[n,h] = <hlin[n,h,:], att_src[h,:]>, same for dst. hlin is bf16.
// ---------------------------------------------------------------------------
__global__ void att_proj(const unsigned short* __restrict__ hlin,
                         const float* __restrict__ att_s,
                         const float* __restrict__ att_d,
                         float* __restrict__ a_src, float* __restrict__ a_dst)
{
    int idx = blockIdx.x * 256 + threadIdx.x;
    if (idx >= NN * HH) return;
    int n = idx >> 3, h = idx & 7;
    const unsigned short* hp = hlin + (size_t)n * DD + h * HIDC;
    const float* as = att_s + h * HIDC;
    const float* ad = att_d + h * HIDC;
    float s1 = 0.f, s2 = 0.f;
#pragma unroll 8
    for (int c = 0; c < HIDC; ++c) {
        float hv = bf2f(hp[c]);
        s1 += hv * as[c]; s2 += hv * ad[c];
    }
    a_src[idx] = s1;
    a_dst[idx] = s2;
}

// ---------------------------------------------------------------------------
// CSR build: histogram over dst (incl. self-loops), scan, scatter src indices.
// ---------------------------------------------------------------------------
__global__ void hist_kernel(const int* __restrict__ ei, int* __restrict__ counts)
{
    int i = blockIdx.x * 256 + threadIdx.x;
    if (i >= ENE) return;
    int dst = (i < EE) ? ei[EE + i] : (i - EE);
    atomicAdd(&counts[dst], 1);
}

__global__ __launch_bounds__(1024) void scan_kernel(const int* __restrict__ counts,
                                                    int* __restrict__ offsets)
{
    __shared__ int sums[1024];
    int t = threadIdx.x;
    int v0 = counts[t*4+0], v1 = counts[t*4+1], v2 = counts[t*4+2], v3 = counts[t*4+3];
    sums[t] = v0 + v1 + v2 + v3;
    __syncthreads();
    for (int off = 1; off < 1024; off <<= 1) {
        int x = (t >= off) ? sums[t - off] : 0;
        __syncthreads();
        sums[t] += x;
        __syncthreads();
    }
    int pre = (t > 0) ? sums[t-1] : 0;
    offsets[t*4+0] = pre;
    offsets[t*4+1] = pre + v0;
    offsets[t*4+2] = pre + v0 + v1;
    offsets[t*4+3] = pre + v0 + v1 + v2;
    if (t == 1023) offsets[4096] = sums[1023];
}

__global__ void scatter_kernel(const int* __restrict__ ei, const int* __restrict__ offs,
                               int* __restrict__ cursor, int* __restrict__ src_sorted)
{
    int i = blockIdx.x * 256 + threadIdx.x;
    if (i >= ENE) return;
    int s, d;
    if (i < EE) { s = ei[i]; d = ei[EE + i]; } else { s = d = i - EE; }
    int pos = atomicAdd(&cursor[d], 1);
    src_sorted[offs[d] + pos] = s;
}

// ---------------------------------------------------------------------------
// GAT aggregation: one block per dst node. hlin is bf16; writes fp32 + bf16.
// ---------------------------------------------------------------------------
__global__ __launch_bounds__(256) void gat_node(const unsigned short* __restrict__ hlin,
                                                const float* __restrict__ a_src,
                                                const float* __restrict__ a_dst,
                                                const int* __restrict__ offs,
                                                const int* __restrict__ src_sorted,
                                                const float* __restrict__ bias,
                                                float* __restrict__ out,
                                                unsigned short* __restrict__ outb)
{
    __shared__ float adst[8];
    __shared__ float emax[8];
    __shared__ float denom[8];
    __shared__ float red[256];
    __shared__ float p_lds[16][8];
    __shared__ int   srcs[16];

    const int n = blockIdx.x, t = threadIdx.x;
    if (t < 8) { adst[t] = a_dst[n * 8 + t]; denom[t] = 0.f; }
    const int off0 = offs[n];
    const int deg  = offs[n+1] - off0;
    __syncthreads();

    const int h = t & 7, slot = t >> 3;
    float mx = -3.0e38f;
    for (int j = slot; j < deg; j += 32) {
        int s = src_sorted[off0 + j];
        mx = fmaxf(mx, a_src[s * 8 + h] + adst[h]);
    }
    red[t] = mx;
    __syncthreads();
    for (int half = 128; half >= 8; half >>= 1) {
        if (t < half) red[t] = fmaxf(red[t], red[t + half]);
        __syncthreads();
    }
    if (t < 8) emax[t] = lrelu02(red[t]);
    __syncthreads();

    float acc0 = 0.f, acc1 = 0.f;
    const int h0 = t >> 6, h1 = (t + 256) >> 6;
    for (int base = 0; base < deg; base += 16) {
        int cnt = min(16, deg - base);
        if (t < cnt * 8) {
            int j = base + (t >> 3);
            int s = src_sorted[off0 + j];
            if ((t & 7) == 0) srcs[t >> 3] = s;
            float x = a_src[s * 8 + (t & 7)] + adst[t & 7];
            float p = __expf(lrelu02(x) - emax[t & 7]);
            p_lds[t >> 3][t & 7] = p;
            atomicAdd(&denom[t & 7], p);
        }
        __syncthreads();
        for (int jj = 0; jj < cnt; ++jj) {
            int s = srcs[jj];
            const unsigned short* hp = hlin + (size_t)s * DD;
            acc0 += p_lds[jj][h0] * bf2f(hp[t]);
            acc1 += p_lds[jj][h1] * bf2f(hp[256 + t]);
        }
        __syncthreads();
    }
    float o0 = acc0 / (denom[h0] + 1e-16f) + bias[t];
    float o1 = acc1 / (denom[h1] + 1e-16f) + bias[256 + t];
    out[(size_t)n * DD + t]        = o0;
    out[(size_t)n * DD + 256 + t]  = o1;
    outb[(size_t)n * DD + t]       = f2bf(o0);
    outb[(size_t)n * DD + 256 + t] = f2bf(o1);
}

// ---------------------------------------------------------------------------
// bf16 MFMA flash attention (unchanged core from round 2); bf16 output.
// ---------------------------------------------------------------------------
__global__ __launch_bounds__(256) void attn_mfma(const unsigned short* __restrict__ qkv,
                                                 unsigned short* __restrict__ aob)
{
    __shared__ __align__(16) unsigned short Ks[64 * 64];
    __shared__ __align__(16) unsigned short Vt[64 * 64];
    __shared__ __align__(16) unsigned short Ps[4 * 16 * 64];

    const int t = threadIdx.x;
    const int w = t >> 6, lane = t & 63;
    const int q15 = lane & 15, g = lane >> 4;
    const int h = blockIdx.y;
    const int qbase = blockIdx.x * 64 + w * 16;

    const unsigned short* qrow = qkv + (size_t)(qbase + q15) * D3 + h * HIDC;
    const short8 qf0 = *(const short8*)(qrow + g * 8);
    const short8 qf1 = *(const short8*)(qrow + 32 + g * 8);

    f32x4 O[4];
#pragma unroll
    for (int db = 0; db < 4; ++db) O[db] = (f32x4){0.f, 0.f, 0.f, 0.f};
    float m_run = -3.0e38f, l_run = 0.f;

    const int r0 = t >> 3, ch = t & 7;
    const int kp = t & 31, dg = t >> 5;

    for (int kb = 0; kb < NN / 64; ++kb) {
        const int kbase = kb * 64;
        {
            const unsigned short* kg = qkv + (size_t)(kbase + r0) * D3 + DD + h * HIDC + ch * 8;
            short8 k0 = *(const short8*)kg;
            short8 k1 = *(const short8*)(kg + (size_t)32 * D3);
            *(short8*)&Ks[(r0 * 64 + ch * 8) ^ ((r0 & 7) << 3)] = k0;
            const int r1 = r0 + 32;
            *(short8*)&Ks[(r1 * 64 + ch * 8) ^ ((r1 & 7) << 3)] = k1;
        }
        {
            const unsigned short* vg = qkv + (size_t)(kbase + 2 * kp) * D3 + 2 * DD + h * HIDC + dg * 8;
            short8 v0 = *(const short8*)vg;
            short8 v1 = *(const short8*)(vg + D3);
#pragma unroll
            for (int i = 0; i < 8; ++i) {
                unsigned int pk = (unsigned int)(unsigned short)v0[i]
                                | ((unsigned int)(unsigned short)v1[i] << 16);
                int d = dg * 8 + i;
                *(unsigned int*)&Vt[(d * 64 + 2 * kp) ^ ((d & 7) << 3)] = pk;
            }
        }
        __syncthreads();

        f32x4 st[4];
#pragma unroll
        for (int kvb = 0; kvb < 4; ++kvb) {
            const int kr = kvb * 16 + q15;
            const short8 kf0 = *(const short8*)&Ks[(kr * 64 + g * 8) ^ ((kr & 7) << 3)];
            const short8 kf1 = *(const short8*)&Ks[(kr * 64 + 32 + g * 8) ^ ((kr & 7) << 3)];
            f32x4 acc = (f32x4){0.f, 0.f, 0.f, 0.f};
            acc = __builtin_amdgcn_mfma_f32_16x16x32_bf16(kf0, qf0, acc, 0, 0, 0);
            acc = __builtin_amdgcn_mfma_f32_16x16x32_bf16(kf1, qf1, acc, 0, 0, 0);
            st[kvb] = acc;
        }

        float mx = -3.0e38f;
#pragma unroll
        for (int kvb = 0; kvb < 4; ++kvb)
#pragma unroll
            for (int r = 0; r < 4; ++r) mx = fmaxf(mx, st[kvb][r]);
        mx = fmaxf(mx, __shfl_xor(mx, 16, 64));
        mx = fmaxf(mx, __shfl_xor(mx, 32, 64));
        const float mnew = fmaxf(m_run, mx);
        const float f = __expf(m_run - mnew);
        float p[16];
        float ls = 0.f;
#pragma unroll
        for (int kvb = 0; kvb < 4; ++kvb)
#pragma unroll
            for (int r = 0; r < 4; ++r) {
                float e = __expf(st[kvb][r] - mnew);
                p[kvb * 4 + r] = e;
                ls += e;
            }
        ls += __shfl_xor(ls, 16, 64);
        ls += __shfl_xor(ls, 32, 64);
        l_run = l_run * f + ls;
        m_run = mnew;
#pragma unroll
        for (int db = 0; db < 4; ++db) O[db] *= f;

        unsigned short* pw = &Ps[w * (16 * 64)];
#pragma unroll
        for (int kvb = 0; kvb < 4; ++kvb) {
            uint2v pk;
            pk.x = (unsigned int)f2bf(p[kvb * 4 + 0]) | ((unsigned int)f2bf(p[kvb * 4 + 1]) << 16);
            pk.y = (unsigned int)f2bf(p[kvb * 4 + 2]) | ((unsigned int)f2bf(p[kvb * 4 + 3]) << 16);
            const int col = kvb * 16 + g * 4;
            *(uint2v*)&pw[(q15 * 64 + col) ^ ((q15 & 7) << 3)] = pk;
        }
        const short8 pf0 = *(const short8*)&pw[(q15 * 64 + g * 8) ^ ((q15 & 7) << 3)];
        const short8 pf1 = *(const short8*)&pw[(q15 * 64 + 32 + g * 8) ^ ((q15 & 7) << 3)];

#pragma unroll
        for (int db = 0; db < 4; ++db) {
            const int vr = db * 16 + q15;
            const short8 vf0 = *(const short8*)&Vt[(vr * 64 + g * 8) ^ ((vr & 7) << 3)];
            const short8 vf1 = *(const short8*)&Vt[(vr * 64 + 32 + g * 8) ^ ((vr & 7) << 3)];
            O[db] = __builtin_amdgcn_mfma_f32_16x16x32_bf16(vf0, pf0, O[db], 0, 0, 0);
            O[db] = __builtin_amdgcn_mfma_f32_16x16x32_bf16(vf1, pf1, O[db], 0, 0, 0);
        }
        __syncthreads();
    }

    const float linv = 1.f / l_run;
#pragma unroll
    for (int db = 0; db < 4; ++db) {
        uint2v pk;
        pk.x = (unsigned int)f2bf(O[db][0] * linv) | ((unsigned int)f2bf(O[db][1] * linv) << 16);
        pk.y = (unsigned int)f2bf(O[db][2] * linv) | ((unsigned int)f2bf(O[db][3] * linv) << 16);
        *(uint2v*)&aob[(size_t)(qbase + q15) * DD + h * HIDC + db * 16 + g * 4] = pk;
    }
}

// ---------------------------------------------------------------------------
// Fused residual + LayerNorm: out = LN(hin + dlt)*g + b; optional bf16 copy.
// ---------------------------------------------------------------------------
__global__ __launch_bounds__(256) void ln_fused(const float* __restrict__ hin,
                                                const float* __restrict__ dlt,
                                                const float* __restrict__ g,
                                                const float* __restrict__ b,
                                                float* __restrict__ out,
                                                unsigned short* __restrict__ outb)
{
    __shared__ float red[256];
    const int r = blockIdx.x, t = threadIdx.x;
    const size_t base = (size_t)r * DD;
    float v0 = hin[base + t] + dlt[base + t];
    float v1 = hin[base + 256 + t] + dlt[base + 256 + t];
    red[t] = v0 + v1;
    __syncthreads();
    for (int off = 128; off > 0; off >>= 1) { if (t < off) red[t] += red[t + off]; __syncthreads(); }
    float mu = red[0] * (1.f / 512.f);
    __syncthreads();
    float d0 = v0 - mu, d1 = v1 - mu;
    red[t] = d0 * d0 + d1 * d1;
    __syncthreads();
    for (int off = 128; off > 0; off >>= 1) { if (t < off) red[t] += red[t + off]; __syncthreads(); }
    float rs = rsqrtf(red[0] * (1.f / 512.f) + 1e-5f);
    float o0 = d0 * rs * g[t] + b[t];
    float o1 = d1 * rs * g[256 + t] + b[256 + t];
    out[base + t]       = o0;
    out[base + 256 + t] = o1;
    if (outb) {
        outb[base + t]       = f2bf(o0);
        outb[base + 256 + t] = f2bf(o1);
    }
}

// ---------------------------------------------------------------------------
extern "C" void kernel_launch(void* const* d_in, const int* in_sizes, int n_in,
                              void* d_out, int out_size, void* d_ws, size_t ws_size,
                              hipStream_t stream)
{
    (void)in_sizes; (void)n_in; (void)out_size; (void)ws_size;

    const float* x        = (const float*)d_in[0];
    const int*   ei       = (const int*)  d_in[1];
    const float* lin_w    = (const float*)d_in[3];
    const float* att_src  = (const float*)d_in[4];
    const float* att_dst  = (const float*)d_in[5];
    const float* gat_bias = (const float*)d_in[6];
    const float* qkv_w    = (const float*)d_in[7];
    const float* qkv_b    = (const float*)d_in[8];
    const float* out_w    = (const float*)d_in[9];
    const float* out_b    = (const float*)d_in[10];
    const float* ln1_g    = (const float*)d_in[11];
    const float* ln1_b    = (const float*)d_in[12];
    const float* ff1_w    = (const float*)d_in[13];
    const float* ff1_b    = (const float*)d_in[14];
    const float* ff2_w    = (const float*)d_in[15];
    const float* ff2_b    = (const float*)d_in[16];
    const float* ln2_g    = (const float*)d_in[17];
    const float* ln2_b    = (const float*)d_in[18];

    char* wsb = (char*)d_ws;
    size_t o = 0;
    auto alloc = [&](size_t bytes) { char* p = wsb + o; o += (bytes + 255) & ~(size_t)255; return p; };

    unsigned short* hlin_bf = (unsigned short*)alloc((size_t)NN * DD * 2);
    unsigned short* hbf     = (unsigned short*)alloc((size_t)NN * DD * 2);
    unsigned short* qkv16   = (unsigned short*)alloc((size_t)NN * D3 * 2);
    unsigned short* aob     = (unsigned short*)alloc((size_t)NN * DD * 2);
    unsigned short* ff1obf  = (unsigned short*)alloc((size_t)NN * DFF2 * 2);
    float* hcur  = (float*)alloc((size_t)NN * DD * 4);
    float* tmp1  = (float*)alloc((size_t)NN * DD * 4);
    float* a_src = (float*)alloc((size_t)NN * HH * 4);
    float* a_dst = (float*)alloc((size_t)NN * HH * 4);
    int* counts     = (int*)alloc(NN * 4);
    int* cursor     = (int*)alloc(NN * 4);
    int* offsets    = (int*)alloc((NN + 1) * 4);
    int* src_sorted = (int*)alloc(ENE * 4);
    unsigned short* xbf    = (unsigned short*)alloc((size_t)NN * IND * 2);
    unsigned short* linwbf = (unsigned short*)alloc((size_t)DD * IND * 2);
    unsigned short* qkvwbf = (unsigned short*)alloc((size_t)2 * D3 * DD * 2);
    unsigned short* outwbf = (unsigned short*)alloc((size_t)2 * DD * DD * 2);
    unsigned short* ff1wbf = (unsigned short*)alloc((size_t)2 * DFF2 * DD * 2);
    unsigned short* ff2wbf = (unsigned short*)alloc((size_t)2 * DD * DFF2 * 2);

    // --- weight/x conversion to bf16 (one pass) ---
    CvtJobs jb;
    jb.src[0] = x;      jb.dst[0] = xbf;    jb.n[0] = NN * IND;
    jb.src[1] = lin_w;  jb.dst[1] = linwbf; jb.n[1] = DD * IND;
    jb.src[2] = qkv_w;  jb.dst[2] = qkvwbf; jb.n[2] = 2 * D3 * DD;
    jb.src[3] = out_w;  jb.dst[3] = outwbf; jb.n[3] = 2 * DD * DD;
    jb.src[4] = ff1_w;  jb.dst[4] = ff1wbf; jb.n[4] = 2 * DFF2 * DD;
    jb.src[5] = ff2_w;  jb.dst[5] = ff2wbf; jb.n[5] = 2 * DD * DFF2;
    int cvt_total = jb.n[0]+jb.n[1]+jb.n[2]+jb.n[3]+jb.n[4]+jb.n[5];
    cvt_many<<<(cvt_total/4 + 255)/256, 256, 0, stream>>>(jb, cvt_total);

    // --- GAT ---
    hipMemsetAsync(counts, 0, 2 * NN * sizeof(int), stream);  // counts + cursor (adjacent)
    gemm_bf16<<<dim3(DD/128, NN/128), 256, 0, stream>>>(xbf, linwbf, nullptr, hlin_bf,
                                                        NN, IND, DD, 1);
    att_proj<<<(NN*HH + 255)/256, 256, 0, stream>>>(hlin_bf, att_src, att_dst, a_src, a_dst);
    hist_kernel<<<(ENE + 255)/256, 256, 0, stream>>>(ei, counts);
    scan_kernel<<<1, 1024, 0, stream>>>(counts, offsets);
    scatter_kernel<<<(ENE + 255)/256, 256, 0, stream>>>(ei, offsets, cursor, src_sorted);
    gat_node<<<NN, 256, 0, stream>>>(hlin_bf, a_src, a_dst, offsets, src_sorted, gat_bias,
                                     hcur, hbf);

    // --- 2 transformer encoder layers (post-norm) ---
    for (int i = 0; i < 2; ++i) {
        gemm_bf16<<<dim3(D3/128, NN/128), 256, 0, stream>>>(hbf, qkvwbf + (size_t)i*D3*DD,
                                                            qkv_b + (size_t)i*D3, qkv16,
                                                            NN, DD, D3, 1 | 4);
        attn_mfma<<<dim3(NN/64, HH), 256, 0, stream>>>(qkv16, aob);
        gemm_bf16<<<dim3(DD/128, NN/128), 256, 0, stream>>>(aob, outwbf + (size_t)i*DD*DD,
                                                            out_b + (size_t)i*DD, tmp1,
                                                            NN, DD, DD, 0);
        ln_fused<<<NN, 256, 0, stream>>>(hcur, tmp1, ln1_g + (size_t)i*DD, ln1_b + (size_t)i*DD,
                                         hcur, hbf);
        gemm_bf16<<<dim3(DFF2/128, NN/128), 256, 0, stream>>>(hbf, ff1wbf + (size_t)i*DFF2*DD,
                                                              ff1_b + (size_t)i*DFF2, ff1obf,
                                                              NN, DD, DFF2, 1 | 2);
        gemm_bf16<<<dim3(DD/128, NN/128), 256, 0, stream>>>(ff1obf, ff2wbf + (size_t)i*DD*DFF2,
                                                            ff2_b + (size_t)i*DD, tmp1,
                                                            NN, DFF2, DD, 0);
        float* outp = (i == 1) ? (float*)d_out : hcur;
        unsigned short* outbp = (i == 1) ? nullptr : hbf;
        ln_fused<<<NN, 256, 0, stream>>>(hcur, tmp1, ln2_g + (size_t)i*DD, ln2_b + (size_t)i*DD,
                                         outp, outbp);
    }
}

// Round 4
// 420.005 us; speedup vs baseline: 5.8682x; 1.0808x over previous
//
#include <hip/hip_runtime.h>
#include <math.h>

// Problem constants (match reference)
#define NN    4096
#define EE    131072
#define ENE   (EE + NN)      // edges + self loops = 135168
#define IND   128
#define HH    8
#define HIDC  64
#define DD    512
#define D3    1536
#define DFF2  256

typedef __attribute__((ext_vector_type(8))) short short8;
typedef __attribute__((ext_vector_type(4))) float f32x4;
typedef __attribute__((ext_vector_type(2))) unsigned int uint2v;

__device__ __forceinline__ float lrelu02(float x) { return x >= 0.f ? x : 0.2f * x; }

// round-to-nearest-even f32 -> bf16 bits (inputs finite)
__device__ __forceinline__ unsigned short f2bf(float x) {
    unsigned int u = __float_as_uint(x);
    u += 0x7fffu + ((u >> 16) & 1u);
    return (unsigned short)(u >> 16);
}
__device__ __forceinline__ float bf2f(unsigned short u) {
    return __uint_as_float((unsigned int)u << 16);
}
// packed RNE f32x2 -> bf16x2 (T12 recipe; D.lo = cvt(%1), D.hi = cvt(%2))
__device__ __forceinline__ unsigned int cvt_pk_bf16(float lo, float hi) {
    unsigned int r;
    asm("v_cvt_pk_bf16_f32 %0, %1, %2" : "=v"(r) : "v"(lo), "v"(hi));
    return r;
}

// ---------------------------------------------------------------------------
// Batched fp32 -> bf16 conversion (weights + x), one launch, 6 segments.
// ---------------------------------------------------------------------------
struct CvtJobs {
    const float* src[6];
    unsigned short* dst[6];
    int n[6];
};

__global__ __launch_bounds__(256) void cvt_many(CvtJobs jb, int total)
{
    int i = (blockIdx.x * 256 + threadIdx.x) * 4;
    if (i >= total) return;
    int s = 0;
    while (i >= jb.n[s]) { i -= jb.n[s]; ++s; }
    float4 v = *(const float4*)(jb.src[s] + i);
    unsigned int lo = (unsigned int)f2bf(v.x) | ((unsigned int)f2bf(v.y) << 16);
    unsigned int hi = (unsigned int)f2bf(v.z) | ((unsigned int)f2bf(v.w) << 16);
    uint2v pk; pk.x = lo; pk.y = hi;
    *(uint2v*)(jb.dst[s] + i) = pk;
}

// ---------------------------------------------------------------------------
// bf16 MFMA GEMM: C[M,N] = A[M,K] @ W[N,K]^T (+bias). 128x128 tile, BK=64,
// 4 waves (2x2), 4x4 16x16x32 fragments per wave. Reg-staged LDS with XOR
// swizzle (chunk ^= row&7) on BOTH write and read (G4 / rule #21).
// flags: bit0 = bf16 out, bit1 = relu, bit2 = scale cols<512 by 0.125 (QKV).
// ---------------------------------------------------------------------------
__global__ __launch_bounds__(256) void gemm_bf16(const unsigned short* __restrict__ A,
                                                 const unsigned short* __restrict__ W,
                                                 const float* __restrict__ bias,
                                                 void* __restrict__ C,
                                                 int M, int K, int N, int flags)
{
    __shared__ __align__(16) unsigned short As[128 * 64];
    __shared__ __align__(16) unsigned short Bs[128 * 64];

    const int t = threadIdx.x, lane = t & 63, w = t >> 6;
    const int wr = w >> 1, wc = w & 1;
    const int bm = blockIdx.y * 128, bn = blockIdx.x * 128;
    const int q = lane & 15, g = lane >> 4;

    f32x4 acc[4][4];
#pragma unroll
    for (int m = 0; m < 4; ++m)
#pragma unroll
        for (int n = 0; n < 4; ++n) acc[m][n] = (f32x4){0.f, 0.f, 0.f, 0.f};

    const int srow = t >> 1, sh = t & 1;
    const unsigned short* Ag = A + (size_t)(bm + srow) * K + sh * 32;
    const unsigned short* Wg = W + (size_t)(bn + srow) * K + sh * 32;
    int wofs[4];
#pragma unroll
    for (int i = 0; i < 4; ++i)
        wofs[i] = srow * 128 + ((((sh * 4 + i) * 16) ^ ((srow & 7) << 4)));

    for (int k0 = 0; k0 < K; k0 += 64) {
        short8 av[4], bv[4];
#pragma unroll
        for (int i = 0; i < 4; ++i) {
            av[i] = *(const short8*)(Ag + k0 + i * 8);
            bv[i] = *(const short8*)(Wg + k0 + i * 8);
        }
        __syncthreads();
#pragma unroll
        for (int i = 0; i < 4; ++i) {
            *(short8*)((char*)As + wofs[i]) = av[i];
            *(short8*)((char*)Bs + wofs[i]) = bv[i];
        }
        __syncthreads();

        short8 af[2][4], bfr[2][4];
#pragma unroll
        for (int m = 0; m < 4; ++m) {
            const int row = wr * 64 + m * 16 + q;
#pragma unroll
            for (int kk = 0; kk < 2; ++kk)
                af[kk][m] = *(const short8*)((const char*)As +
                    row * 128 + ((((kk * 4 + g) * 16) ^ ((row & 7) << 4))));
        }
#pragma unroll
        for (int n = 0; n < 4; ++n) {
            const int row = wc * 64 + n * 16 + q;
#pragma unroll
            for (int kk = 0; kk < 2; ++kk)
                bfr[kk][n] = *(const short8*)((const char*)Bs +
                    row * 128 + ((((kk * 4 + g) * 16) ^ ((row & 7) << 4))));
        }
#pragma unroll
        for (int kk = 0; kk < 2; ++kk)
#pragma unroll
            for (int m = 0; m < 4; ++m)
#pragma unroll
                for (int n = 0; n < 4; ++n)
                    acc[m][n] = __builtin_amdgcn_mfma_f32_16x16x32_bf16(
                        bfr[kk][n], af[kk][m], acc[m][n], 0, 0, 0);
    }

    const int obf = flags & 1, orelu = flags & 2, oqs = flags & 4;
#pragma unroll
    for (int m = 0; m < 4; ++m) {
        const int row = bm + wr * 64 + m * 16 + q;
#pragma unroll
        for (int n = 0; n < 4; ++n) {
            const int col0 = bn + wc * 64 + n * 16 + g * 4;
            f32x4 v = acc[m][n];
            if (bias) {
                float4 bv4 = *(const float4*)(bias + col0);
                v[0] += bv4.x; v[1] += bv4.y; v[2] += bv4.z; v[3] += bv4.w;
            }
            if (oqs && col0 < DD) {
                v[0] *= 0.125f; v[1] *= 0.125f; v[2] *= 0.125f; v[3] *= 0.125f;
            }
            if (orelu) {
                v[0] = fmaxf(v[0], 0.f); v[1] = fmaxf(v[1], 0.f);
                v[2] = fmaxf(v[2], 0.f); v[3] = fmaxf(v[3], 0.f);
            }
            if (obf) {
                uint2v pk;
                pk.x = (unsigned int)f2bf(v[0]) | ((unsigned int)f2bf(v[1]) << 16);
                pk.y = (unsigned int)f2bf(v[2]) | ((unsigned int)f2bf(v[3]) << 16);
                *(uint2v*)((unsigned short*)C + (size_t)row * N + col0) = pk;
            } else {
                float4 o; o.x = v[0]; o.y = v[1]; o.z = v[2]; o.w = v[3];
                *(float4*)((float*)C + (size_t)row * N + col0) = o;
            }
        }
    }
}

// ---------------------------------------------------------------------------
// a_src[n,h] = <hlin[n,h,:], att_src[h,:]>, same for dst. hlin is bf16.
// ---------------------------------------------------------------------------
__global__ void att_proj(const unsigned short* __restrict__ hlin,
                         const float* __restrict__ att_s,
                         const float* __restrict__ att_d,
                         float* __restrict__ a_src, float* __restrict__ a_dst)
{
    int idx = blockIdx.x * 256 + threadIdx.x;
    if (idx >= NN * HH) return;
    int n = idx >> 3, h = idx & 7;
    const unsigned short* hp = hlin + (size_t)n * DD + h * HIDC;
    const float* as = att_s + h * HIDC;
    const float* ad = att_d + h * HIDC;
    float s1 = 0.f, s2 = 0.f;
#pragma unroll 8
    for (int c = 0; c < HIDC; ++c) {
        float hv = bf2f(hp[c]);
        s1 += hv * as[c]; s2 += hv * ad[c];
    }
    a_src[idx] = s1;
    a_dst[idx] = s2;
}

// ---------------------------------------------------------------------------
// CSR build: histogram over dst (incl. self-loops), scan, scatter src indices.
// ---------------------------------------------------------------------------
__global__ void hist_kernel(const int* __restrict__ ei, int* __restrict__ counts)
{
    int i = blockIdx.x * 256 + threadIdx.x;
    if (i >= ENE) return;
    int dst = (i < EE) ? ei[EE + i] : (i - EE);
    atomicAdd(&counts[dst], 1);
}

__global__ __launch_bounds__(1024) void scan_kernel(const int* __restrict__ counts,
                                                    int* __restrict__ offsets)
{
    __shared__ int sums[1024];
    int t = threadIdx.x;
    int v0 = counts[t*4+0], v1 = counts[t*4+1], v2 = counts[t*4+2], v3 = counts[t*4+3];
    sums[t] = v0 + v1 + v2 + v3;
    __syncthreads();
    for (int off = 1; off < 1024; off <<= 1) {
        int x = (t >= off) ? sums[t - off] : 0;
        __syncthreads();
        sums[t] += x;
        __syncthreads();
    }
    int pre = (t > 0) ? sums[t-1] : 0;
    offsets[t*4+0] = pre;
    offsets[t*4+1] = pre + v0;
    offsets[t*4+2] = pre + v0 + v1;
    offsets[t*4+3] = pre + v0 + v1 + v2;
    if (t == 1023) offsets[4096] = sums[1023];
}

__global__ void scatter_kernel(const int* __restrict__ ei, const int* __restrict__ offs,
                               int* __restrict__ cursor, int* __restrict__ src_sorted)
{
    int i = blockIdx.x * 256 + threadIdx.x;
    if (i >= ENE) return;
    int s, d;
    if (i < EE) { s = ei[i]; d = ei[EE + i]; } else { s = d = i - EE; }
    int pos = atomicAdd(&cursor[d], 1);
    src_sorted[offs[d] + pos] = s;
}

// ---------------------------------------------------------------------------
// GAT aggregation: one block per dst node. hlin is bf16; writes fp32 + bf16.
// ---------------------------------------------------------------------------
__global__ __launch_bounds__(256) void gat_node(const unsigned short* __restrict__ hlin,
                                                const float* __restrict__ a_src,
                                                const float* __restrict__ a_dst,
                                                const int* __restrict__ offs,
                                                const int* __restrict__ src_sorted,
                                                const float* __restrict__ bias,
                                                float* __restrict__ out,
                                                unsigned short* __restrict__ outb)
{
    __shared__ float adst[8];
    __shared__ float emax[8];
    __shared__ float denom[8];
    __shared__ float red[256];
    __shared__ float p_lds[16][8];
    __shared__ int   srcs[16];

    const int n = blockIdx.x, t = threadIdx.x;
    if (t < 8) { adst[t] = a_dst[n * 8 + t]; denom[t] = 0.f; }
    const int off0 = offs[n];
    const int deg  = offs[n+1] - off0;
    __syncthreads();

    const int h = t & 7, slot = t >> 3;
    float mx = -3.0e38f;
    for (int j = slot; j < deg; j += 32) {
        int s = src_sorted[off0 + j];
        mx = fmaxf(mx, a_src[s * 8 + h] + adst[h]);
    }
    red[t] = mx;
    __syncthreads();
    for (int half = 128; half >= 8; half >>= 1) {
        if (t < half) red[t] = fmaxf(red[t], red[t + half]);
        __syncthreads();
    }
    if (t < 8) emax[t] = lrelu02(red[t]);
    __syncthreads();

    float acc0 = 0.f, acc1 = 0.f;
    const int h0 = t >> 6, h1 = (t + 256) >> 6;
    for (int base = 0; base < deg; base += 16) {
        int cnt = min(16, deg - base);
        if (t < cnt * 8) {
            int j = base + (t >> 3);
            int s = src_sorted[off0 + j];
            if ((t & 7) == 0) srcs[t >> 3] = s;
            float x = a_src[s * 8 + (t & 7)] + adst[t & 7];
            float p = __expf(lrelu02(x) - emax[t & 7]);
            p_lds[t >> 3][t & 7] = p;
            atomicAdd(&denom[t & 7], p);
        }
        __syncthreads();
        for (int jj = 0; jj < cnt; ++jj) {
            int s = srcs[jj];
            const unsigned short* hp = hlin + (size_t)s * DD;
            acc0 += p_lds[jj][h0] * bf2f(hp[t]);
            acc1 += p_lds[jj][h1] * bf2f(hp[256 + t]);
        }
        __syncthreads();
    }
    float o0 = acc0 / (denom[h0] + 1e-16f) + bias[t];
    float o1 = acc1 / (denom[h1] + 1e-16f) + bias[256 + t];
    out[(size_t)n * DD + t]        = o0;
    out[(size_t)n * DD + 256 + t]  = o1;
    outb[(size_t)n * DD + t]       = f2bf(o0);
    outb[(size_t)n * DD + 256 + t] = f2bf(o1);
}

// ---------------------------------------------------------------------------
// bf16 MFMA flash attention, v2. Grid (NN/64, HH), 256 thr = 4 waves, wave
// owns 16 Q rows. KVBLK=128, T14 async reg-staging (issue-early/write-late),
// T13 defer-max (THR=8), T12 cvt_pk for P, T5 setprio around MFMA.
// Swapped QK^T and swapped PV (q = lane&15 everywhere); XOR swizzle
// (8-short chunk ^= row&7) on both write and read of K/Vt/P.
// ---------------------------------------------------------------------------
#define KVB 128
#define NT  (NN / KVB)

__global__ __launch_bounds__(256) void attn_mfma(const unsigned short* __restrict__ qkv,
                                                 unsigned short* __restrict__ aob)
{
    __shared__ __align__(16) unsigned short Ks[KVB * 64];       // [k][c]
    __shared__ __align__(16) unsigned short Vt[64 * KVB];       // [d][k]
    __shared__ __align__(16) unsigned short Ps[4 * 16 * KVB];   // per-wave [q][k]

    const int t = threadIdx.x;
    const int w = t >> 6, lane = t & 63;
    const int q15 = lane & 15, g = lane >> 4;
    const int h = blockIdx.y;
    const int qbase = blockIdx.x * 64 + w * 16;

    // Q fragments (0.125 pre-folded by gemm QKV epilogue)
    const unsigned short* qrow = qkv + (size_t)(qbase + q15) * D3 + h * HIDC;
    const short8 qf0 = *(const short8*)(qrow + g * 8);
    const short8 qf1 = *(const short8*)(qrow + 32 + g * 8);

    f32x4 O[4];
#pragma unroll
    for (int db = 0; db < 4; ++db) O[db] = (f32x4){0.f, 0.f, 0.f, 0.f};
    float m_run = -3.0e38f, l_run = 0.f;

    // staging assignments
    const int kr_s = t >> 1, sh = t & 1;          // K: row kr_s, 32-col half sh
    const int kq = t & 31, dg = t >> 5;           // V: k-quad kq (rows 4kq..+3), d-chunk dg (8 d)
    const unsigned short* Kg = qkv + (size_t)kr_s * D3 + DD + h * HIDC + sh * 32;
    const unsigned short* Vg = qkv + (size_t)(4 * kq) * D3 + 2 * DD + h * HIDC + dg * 8;

    short8 kreg[4], vreg[4];

    auto LOAD_KV = [&](int kb) {
        const size_t off = (size_t)kb * KVB * D3;
#pragma unroll
        for (int i = 0; i < 4; ++i) kreg[i] = *(const short8*)(Kg + off + i * 8);
#pragma unroll
        for (int j = 0; j < 4; ++j) vreg[j] = *(const short8*)(Vg + off + (size_t)j * D3);
    };
    auto WRITE_KV = [&]() {
#pragma unroll
        for (int i = 0; i < 4; ++i)
            *(short8*)&Ks[(kr_s * 64 + (sh * 4 + i) * 8) ^ ((kr_s & 7) << 3)] = kreg[i];
        const unsigned int* w0 = (const unsigned int*)&vreg[0];
        const unsigned int* w1 = (const unsigned int*)&vreg[1];
        const unsigned int* w2 = (const unsigned int*)&vreg[2];
        const unsigned int* w3 = (const unsigned int*)&vreg[3];
#pragma unroll
        for (int i = 0; i < 8; ++i) {
            const int d = dg * 8 + i;
            unsigned int a0 = w0[i >> 1], a1 = w1[i >> 1], a2 = w2[i >> 1], a3 = w3[i >> 1];
            unsigned int pk01, pk23;
            if (i & 1) {
                pk01 = (a1 & 0xffff0000u) | (a0 >> 16);
                pk23 = (a3 & 0xffff0000u) | (a2 >> 16);
            } else {
                pk01 = (a1 << 16) | (a0 & 0xffffu);
                pk23 = (a3 << 16) | (a2 & 0xffffu);
            }
            uint2v pk; pk.x = pk01; pk.y = pk23;
            *(uint2v*)&Vt[(d * KVB + 4 * kq) ^ ((d & 7) << 3)] = pk;
        }
    };

    // prologue: tile 0 into LDS
    LOAD_KV(0);
    WRITE_KV();
    __syncthreads();

    unsigned short* pw = &Ps[w * (16 * KVB)];

    for (int kb = 0; kb < NT; ++kb) {
        if (kb + 1 < NT) LOAD_KV(kb + 1);      // T14: issue early

        // --- QK^T swapped: st[kvb] holds S^T[kv = kvb*16 + (g*4+r)][q = q15]
        f32x4 st[8];
        __builtin_amdgcn_s_setprio(1);
#pragma unroll
        for (int kvb = 0; kvb < 8; ++kvb) {
            const int kr = kvb * 16 + q15;
            const short8 kf0 = *(const short8*)&Ks[(kr * 64 + g * 8) ^ ((kr & 7) << 3)];
            const short8 kf1 = *(const short8*)&Ks[(kr * 64 + 32 + g * 8) ^ ((kr & 7) << 3)];
            f32x4 acc = (f32x4){0.f, 0.f, 0.f, 0.f};
            acc = __builtin_amdgcn_mfma_f32_16x16x32_bf16(kf0, qf0, acc, 0, 0, 0);
            acc = __builtin_amdgcn_mfma_f32_16x16x32_bf16(kf1, qf1, acc, 0, 0, 0);
            st[kvb] = acc;
        }
        __builtin_amdgcn_s_setprio(0);

        // --- online softmax with defer-max (T13, THR=8)
        float pmax = -3.0e38f;
#pragma unroll
        for (int kvb = 0; kvb < 8; ++kvb) {
            float m01 = fmaxf(st[kvb][0], st[kvb][1]);
            float m23 = fmaxf(st[kvb][2], st[kvb][3]);
            pmax = fmaxf(pmax, fmaxf(m01, m23));
        }
        pmax = fmaxf(pmax, __shfl_xor(pmax, 16, 64));
        pmax = fmaxf(pmax, __shfl_xor(pmax, 32, 64));
        if (!__all(pmax <= m_run + 8.f)) {
            const float mnew = fmaxf(m_run, pmax);
            const float f = __expf(m_run - mnew);
            l_run *= f;
#pragma unroll
            for (int db = 0; db < 4; ++db) O[db] *= f;
            m_run = mnew;
        }
        float p[32];
        float ls = 0.f;
#pragma unroll
        for (int kvb = 0; kvb < 8; ++kvb)
#pragma unroll
            for (int r = 0; r < 4; ++r) {
                float e = __expf(st[kvb][r] - m_run);
                p[kvb * 4 + r] = e;
                ls += e;
            }
        ls += __shfl_xor(ls, 16, 64);
        ls += __shfl_xor(ls, 32, 64);
        l_run += ls;

        // --- pack P -> per-wave LDS rows (q = q15), T12 cvt_pk
#pragma unroll
        for (int kvb = 0; kvb < 8; ++kvb) {
            uint2v pk;
            pk.x = cvt_pk_bf16(p[kvb * 4 + 0], p[kvb * 4 + 1]);
            pk.y = cvt_pk_bf16(p[kvb * 4 + 2], p[kvb * 4 + 3]);
            *(uint2v*)&pw[(q15 * KVB + kvb * 16 + g * 4) ^ ((q15 & 7) << 3)] = pk;
        }
        short8 pf[4];
#pragma unroll
        for (int ks = 0; ks < 4; ++ks)
            pf[ks] = *(const short8*)&pw[(q15 * KVB + ks * 32 + g * 8) ^ ((q15 & 7) << 3)];

        // --- PV swapped: O^T[d][q] += Vt @ P^T
        __builtin_amdgcn_s_setprio(1);
#pragma unroll
        for (int db = 0; db < 4; ++db) {
            const int vr = db * 16 + q15;
#pragma unroll
            for (int ks = 0; ks < 4; ++ks) {
                const short8 vf = *(const short8*)&Vt[(vr * KVB + ks * 32 + g * 8) ^ ((vr & 7) << 3)];
                O[db] = __builtin_amdgcn_mfma_f32_16x16x32_bf16(vf, pf[ks], O[db], 0, 0, 0);
            }
        }
        __builtin_amdgcn_s_setprio(0);

        __syncthreads();                        // all waves done reading Ks/Vt
        if (kb + 1 < NT) {
            WRITE_KV();                         // T14: write late (vmcnt waits here)
            __syncthreads();
        }
    }

    const float linv = 1.f / l_run;
#pragma unroll
    for (int db = 0; db < 4; ++db) {
        uint2v pk;
        pk.x = (unsigned int)f2bf(O[db][0] * linv) | ((unsigned int)f2bf(O[db][1] * linv) << 16);
        pk.y = (unsigned int)f2bf(O[db][2] * linv) | ((unsigned int)f2bf(O[db][3] * linv) << 16);
        *(uint2v*)&aob[(size_t)(qbase + q15) * DD + h * HIDC + db * 16 + g * 4] = pk;
    }
}

// ---------------------------------------------------------------------------
// Fused residual + LayerNorm: out = LN(hin + dlt)*g + b; optional bf16 copy.
// ---------------------------------------------------------------------------
__global__ __launch_bounds__(256) void ln_fused(const float* __restrict__ hin,
                                                const float* __restrict__ dlt,
                                                const float* __restrict__ g,
                                                const float* __restrict__ b,
                                                float* __restrict__ out,
                                                unsigned short* __restrict__ outb)
{
    __shared__ float red[256];
    const int r = blockIdx.x, t = threadIdx.x;
    const size_t base = (size_t)r * DD;
    float v0 = hin[base + t] + dlt[base + t];
    float v1 = hin[base + 256 + t] + dlt[base + 256 + t];
    red[t] = v0 + v1;
    __syncthreads();
    for (int off = 128; off > 0; off >>= 1) { if (t < off) red[t] += red[t + off]; __syncthreads(); }
    float mu = red[0] * (1.f / 512.f);
    __syncthreads();
    float d0 = v0 - mu, d1 = v1 - mu;
    red[t] = d0 * d0 + d1 * d1;
    __syncthreads();
    for (int off = 128; off > 0; off >>= 1) { if (t < off) red[t] += red[t + off]; __syncthreads(); }
    float rs = rsqrtf(red[0] * (1.f / 512.f) + 1e-5f);
    float o0 = d0 * rs * g[t] + b[t];
    float o1 = d1 * rs * g[256 + t] + b[256 + t];
    out[base + t]       = o0;
    out[base + 256 + t] = o1;
    if (outb) {
        outb[base + t]       = f2bf(o0);
        outb[base + 256 + t] = f2bf(o1);
    }
}

// ---------------------------------------------------------------------------
extern "C" void kernel_launch(void* const* d_in, const int* in_sizes, int n_in,
                              void* d_out, int out_size, void* d_ws, size_t ws_size,
                              hipStream_t stream)
{
    (void)in_sizes; (void)n_in; (void)out_size; (void)ws_size;

    const float* x        = (const float*)d_in[0];
    const int*   ei       = (const int*)  d_in[1];
    const float* lin_w    = (const float*)d_in[3];
    const float* att_src  = (const float*)d_in[4];
    const float* att_dst  = (const float*)d_in[5];
    const float* gat_bias = (const float*)d_in[6];
    const float* qkv_w    = (const float*)d_in[7];
    const float* qkv_b    = (const float*)d_in[8];
    const float* out_w    = (const float*)d_in[9];
    const float* out_b    = (const float*)d_in[10];
    const float* ln1_g    = (const float*)d_in[11];
    const float* ln1_b    = (const float*)d_in[12];
    const float* ff1_w    = (const float*)d_in[13];
    const float* ff1_b    = (const float*)d_in[14];
    const float* ff2_w    = (const float*)d_in[15];
    const float* ff2_b    = (const float*)d_in[16];
    const float* ln2_g    = (const float*)d_in[17];
    const float* ln2_b    = (const float*)d_in[18];

    char* wsb = (char*)d_ws;
    size_t o = 0;
    auto alloc = [&](size_t bytes) { char* p = wsb + o; o += (bytes + 255) & ~(size_t)255; return p; };

    unsigned short* hlin_bf = (unsigned short*)alloc((size_t)NN * DD * 2);
    unsigned short* hbf     = (unsigned short*)alloc((size_t)NN * DD * 2);
    unsigned short* qkv16   = (unsigned short*)alloc((size_t)NN * D3 * 2);
    unsigned short* aob     = (unsigned short*)alloc((size_t)NN * DD * 2);
    unsigned short* ff1obf  = (unsigned short*)alloc((size_t)NN * DFF2 * 2);
    float* hcur  = (float*)alloc((size_t)NN * DD * 4);
    float* tmp1  = (float*)alloc((size_t)NN * DD * 4);
    float* a_src = (float*)alloc((size_t)NN * HH * 4);
    float* a_dst = (float*)alloc((size_t)NN * HH * 4);
    int* counts     = (int*)alloc(NN * 4);
    int* cursor     = (int*)alloc(NN * 4);
    int* offsets    = (int*)alloc((NN + 1) * 4);
    int* src_sorted = (int*)alloc(ENE * 4);
    unsigned short* xbf    = (unsigned short*)alloc((size_t)NN * IND * 2);
    unsigned short* linwbf = (unsigned short*)alloc((size_t)DD * IND * 2);
    unsigned short* qkvwbf = (unsigned short*)alloc((size_t)2 * D3 * DD * 2);
    unsigned short* outwbf = (unsigned short*)alloc((size_t)2 * DD * DD * 2);
    unsigned short* ff1wbf = (unsigned short*)alloc((size_t)2 * DFF2 * DD * 2);
    unsigned short* ff2wbf = (unsigned short*)alloc((size_t)2 * DD * DFF2 * 2);

    // --- weight/x conversion to bf16 (one pass) ---
    CvtJobs jb;
    jb.src[0] = x;      jb.dst[0] = xbf;    jb.n[0] = NN * IND;
    jb.src[1] = lin_w;  jb.dst[1] = linwbf; jb.n[1] = DD * IND;
    jb.src[2] = qkv_w;  jb.dst[2] = qkvwbf; jb.n[2] = 2 * D3 * DD;
    jb.src[3] = out_w;  jb.dst[3] = outwbf; jb.n[3] = 2 * DD * DD;
    jb.src[4] = ff1_w;  jb.dst[4] = ff1wbf; jb.n[4] = 2 * DFF2 * DD;
    jb.src[5] = ff2_w;  jb.dst[5] = ff2wbf; jb.n[5] = 2 * DD * DFF2;
    int cvt_total = jb.n[0]+jb.n[1]+jb.n[2]+jb.n[3]+jb.n[4]+jb.n[5];
    cvt_many<<<(cvt_total/4 + 255)/256, 256, 0, stream>>>(jb, cvt_total);

    // --- GAT ---
    hipMemsetAsync(counts, 0, 2 * NN * sizeof(int), stream);  // counts + cursor (adjacent)
    gemm_bf16<<<dim3(DD/128, NN/128), 256, 0, stream>>>(xbf, linwbf, nullptr, hlin_bf,
                                                        NN, IND, DD, 1);
    att_proj<<<(NN*HH + 255)/256, 256, 0, stream>>>(hlin_bf, att_src, att_dst, a_src, a_dst);
    hist_kernel<<<(ENE + 255)/256, 256, 0, stream>>>(ei, counts);
    scan_kernel<<<1, 1024, 0, stream>>>(counts, offsets);
    scatter_kernel<<<(ENE + 255)/256, 256, 0, stream>>>(ei, offsets, cursor, src_sorted);
    gat_node<<<NN, 256, 0, stream>>>(hlin_bf, a_src, a_dst, offsets, src_sorted, gat_bias,
                                     hcur, hbf);

    // --- 2 transformer encoder layers (post-norm) ---
    for (int i = 0; i < 2; ++i) {
        gemm_bf16<<<dim3(D3/128, NN/128), 256, 0, stream>>>(hbf, qkvwbf + (size_t)i*D3*DD,
                                                            qkv_b + (size_t)i*D3, qkv16,
                                                            NN, DD, D3, 1 | 4);
        attn_mfma<<<dim3(NN/64, HH), 256, 0, stream>>>(qkv16, aob);
        gemm_bf16<<<dim3(DD/128, NN/128), 256, 0, stream>>>(aob, outwbf + (size_t)i*DD*DD,
                                                            out_b + (size_t)i*DD, tmp1,
                                                            NN, DD, DD, 0);
        ln_fused<<<NN, 256, 0, stream>>>(hcur, tmp1, ln1_g + (size_t)i*DD, ln1_b + (size_t)i*DD,
                                         hcur, hbf);
        gemm_bf16<<<dim3(DFF2/128, NN/128), 256, 0, stream>>>(hbf, ff1wbf + (size_t)i*DFF2*DD,
                                                              ff1_b + (size_t)i*DFF2, ff1obf,
                                                              NN, DD, DFF2, 1 | 2);
        gemm_bf16<<<dim3(DD/128, NN/128), 256, 0, stream>>>(ff1obf, ff2wbf + (size_t)i*DD*DFF2,
                                                            ff2_b + (size_t)i*DD, tmp1,
                                                            NN, DFF2, DD, 0);
        float* outp = (i == 1) ? (float*)d_out : hcur;
        unsigned short* outbp = (i == 1) ? nullptr : hbf;
        ln_fused<<<NN, 256, 0, stream>>>(hcur, tmp1, ln2_g + (size_t)i*DD, ln2_b + (size_t)i*DD,
                                         outp, outbp);
    }
}